// Round 9
// baseline (9700.605 us; speedup 1.0000x reference)
//
#include <hip/hip_runtime.h>

typedef unsigned short u16;
typedef __bf16 bf16x8 __attribute__((ext_vector_type(8)));
typedef float f32x4 __attribute__((ext_vector_type(4)));
typedef float f4 __attribute__((ext_vector_type(4)));
typedef unsigned short u16x8 __attribute__((ext_vector_type(8)));
typedef unsigned short u16x4 __attribute__((ext_vector_type(4)));

#define BB 1024
#define SS 256
#define DD 300
#define HH 150
#define GG 600
#define VV 21257
#define VPAD 21376      // 167*128
#define KSTR 320        // padded K stride for h1 / emb table
#define GSTR 600        // gate row stride (u16), layout [jj][4 gates] interleaved
#define WK 160          // padded Whh K stride
#define L2E 1.442695041f
#define L2E2 2.885390082f

static __device__ __forceinline__ float bf2f(u16 u){
  unsigned v = ((unsigned)u) << 16;
  return __builtin_bit_cast(float, v);
}
static __device__ __forceinline__ u16 f2bf(float f){
  unsigned u = __builtin_bit_cast(unsigned, f);
  u = u + 0x7FFFu + ((u >> 16) & 1u);
  return (u16)(u >> 16);
}
// inputs PRE-SCALED by log2e (sig) / 2log2e (tanh)
static __device__ __forceinline__ float fsig2(float p){
  return __builtin_amdgcn_rcpf(1.0f + __builtin_amdgcn_exp2f(-p));
}
static __device__ __forceinline__ float ftanh2(float p){
  return 2.0f * __builtin_amdgcn_rcpf(1.0f + __builtin_amdgcn_exp2f(-p)) - 1.0f;
}

// ---------------- lengths from mask ----------------
__global__ void k_len(const int* __restrict__ mask, int* __restrict__ len){
  __shared__ int red[256];
  int b = blockIdx.x, t = threadIdx.x;
  red[t] = (mask[b*SS + t] != 0) ? 1 : 0;
  __syncthreads();
  for (int o = 128; o > 0; o >>= 1){
    if (t < o) red[t] += red[t+o];
    __syncthreads();
  }
  if (t == 0) len[b] = red[0];
}

// ---------------- deterministic rank sort by length (ascending) ----------------
__global__ void k_sort(const int* __restrict__ len, int* __restrict__ perm){
  __shared__ int L[1024];
  int b = threadIdx.x;
  int l = len[b];
  L[b] = l;
  __syncthreads();
  int r = 0;
  for (int j = 0; j < 1024; ++j){
    int lj = L[j];
    r += (lj < l) || (lj == l && j < b);
  }
  perm[r] = b;
}

// ---------------- weight pad/convert f32 -> bf16, gate-row pre-scale by log2e ----------------
struct PrepW {
  const float* src[8];
  u16* dst[8];
  int R[8], C[8], DR[8], DC[8];
};
__global__ void k_prepw(PrepW p){
  int z = blockIdx.y;
  int n = p.DR[z]*p.DC[z];
  for (int i = blockIdx.x*256 + threadIdx.x; i < n; i += 800*256){
    int r = i / p.DC[z], c = i - r*p.DC[z];
    float v = (r < p.R[z] && c < p.C[z]) ? p.src[z][r*p.C[z] + c] : 0.f;
    float sc = (r >= 300 && r < 450) ? L2E2 : L2E;   // g-gate rows get 2*log2e
    p.dst[z][i] = f2bf(v * sc);
  }
}
struct PrepB { const float* src[4]; float* dst[4]; };
__global__ void k_prepb(PrepB p){
  int z = blockIdx.y;
  int i = blockIdx.x*256 + threadIdx.x;
  if (i < 640){
    float v = (i < GG) ? p.src[z][i] : 0.f;
    float sc = (i >= 300 && i < 450) ? L2E2 : L2E;
    p.dst[z][i] = v * sc;
  }
}

// ---------------- embedding table pad/convert: [VPAD][KSTR] bf16, row 0 zeroed ----------------
__global__ void k_prepemb(const float* __restrict__ emb, u16* __restrict__ dst){
  long i = (long)blockIdx.x*256 + threadIdx.x;
  if (i >= (long)VPAD*KSTR) return;
  int r = (int)(i / KSTR), c = (int)(i - (long)r*KSTR);
  float v = (r >= 1 && r < VV && c < DD) ? emb[(size_t)r*DD + c] : 0.f;
  dst[i] = f2bf(v);
}

// ---------------- register-fragment GEMM: no LDS, no barriers ----------------
// out[m][(n%150)*4 + n/150] = bf16( sum_k A[m][k]*W[n][k] + bias[n] )
// per wave: 64x80 tile; block = 8 waves = 128x320; grid(M/128, 2, ndir)
__launch_bounds__(512, 2)
__global__ void k_gemm(const u16* __restrict__ A,
                       const u16* __restrict__ Wf, const u16* __restrict__ Wb,
                       const float* __restrict__ bsf, const float* __restrict__ bsb,
                       u16* __restrict__ of, u16* __restrict__ ob)
{
  const u16* W = blockIdx.z ? Wb : Wf;
  const float* bias = blockIdx.z ? bsb : bsf;
  u16* outp = blockIdx.z ? ob : of;

  int tid = threadIdx.x;
  int l = tid & 63, w = tid >> 6;
  int lo = l & 15, hi = l >> 4;
  int wm = w >> 2, wn = w & 3;
  int m0 = blockIdx.x * 128;
  int n0 = blockIdx.y * 320;

  const u16* Abase = A + (size_t)(m0 + wm*64 + lo)*KSTR + hi*8;
  const u16* Bbase = W + (size_t)(n0 + wn*80 + lo)*KSTR + hi*8;

  u16x8 avA[4], bvA[5], avB[4], bvB[5];
  #pragma unroll
  for (int mt = 0; mt < 4; ++mt) avA[mt] = *(const u16x8*)(Abase + (size_t)mt*16*KSTR);
  #pragma unroll
  for (int nt = 0; nt < 5; ++nt) bvA[nt] = *(const u16x8*)(Bbase + (size_t)nt*16*KSTR);

  f32x4 zero = {0.f, 0.f, 0.f, 0.f};
  f32x4 acc[4][5];
  #pragma unroll
  for (int a = 0; a < 4; ++a)
    #pragma unroll
    for (int b = 0; b < 5; ++b) acc[a][b] = zero;

  for (int kk = 0; kk < 10; kk += 2){
    {  // prefetch odd set (kk+1 <= 9 always)
      int kc = (kk+1)*32;
      #pragma unroll
      for (int mt = 0; mt < 4; ++mt) avB[mt] = *(const u16x8*)(Abase + (size_t)mt*16*KSTR + kc);
      #pragma unroll
      for (int nt = 0; nt < 5; ++nt) bvB[nt] = *(const u16x8*)(Bbase + (size_t)nt*16*KSTR + kc);
    }
    #pragma unroll
    for (int mt = 0; mt < 4; ++mt)
      #pragma unroll
      for (int nt = 0; nt < 5; ++nt)
        acc[mt][nt] = __builtin_amdgcn_mfma_f32_16x16x32_bf16(
            __builtin_bit_cast(bf16x8, avA[mt]),
            __builtin_bit_cast(bf16x8, bvA[nt]),
            acc[mt][nt], 0, 0, 0);
    if (kk + 2 < 10){  // prefetch next even set
      int kc = (kk+2)*32;
      #pragma unroll
      for (int mt = 0; mt < 4; ++mt) avA[mt] = *(const u16x8*)(Abase + (size_t)mt*16*KSTR + kc);
      #pragma unroll
      for (int nt = 0; nt < 5; ++nt) bvA[nt] = *(const u16x8*)(Bbase + (size_t)nt*16*KSTR + kc);
    }
    #pragma unroll
    for (int mt = 0; mt < 4; ++mt)
      #pragma unroll
      for (int nt = 0; nt < 5; ++nt)
        acc[mt][nt] = __builtin_amdgcn_mfma_f32_16x16x32_bf16(
            __builtin_bit_cast(bf16x8, avB[mt]),
            __builtin_bit_cast(bf16x8, bvB[nt]),
            acc[mt][nt], 0, 0, 0);
  }

  #pragma unroll
  for (int mt = 0; mt < 4; ++mt){
    #pragma unroll
    for (int nt = 0; nt < 5; ++nt){
      int col = n0 + wn*80 + nt*16 + lo;
      if (col < GG){
        float bsv = bias[col];
        int g = (col >= 450) ? 3 : (col >= 300) ? 2 : (col >= 150) ? 1 : 0;
        int cofs = (col - g*150)*4 + g;   // interleaved [jj][gate]
        #pragma unroll
        for (int r = 0; r < 4; ++r){
          int row = m0 + wm*64 + mt*16 + hi*4 + r;
          outp[(size_t)row*GSTR + cofs] = f2bf(acc[mt][nt][r] + bsv);
        }
      }
    }
  }
}

// ---------------- merged recurrence: TWO adjacent same-dir tiles per WG ----------------
// Round-6 macro style (NO lambdas / NO runtime-indexed arrays -> registers, not scratch).
// 640 thr = 10 waves; wave w owns jj in [16w,16w+16); lane holds all 4 gates of its jj.
#define MFMA5(A0,A1,A2,A3, HSM, PB)                                             \
  { _Pragma("unroll")                                                           \
    for (int ks = 0; ks < 5; ++ks){                                             \
      u16x8 a_ = *(const u16x8*)&HSM[PB][lo*168 + ks*32 + hi*8];                \
      A0 = __builtin_amdgcn_mfma_f32_16x16x32_bf16(                             \
          __builtin_bit_cast(bf16x8,a_), __builtin_bit_cast(bf16x8,bw[0][ks]), A0,0,0,0); \
      A1 = __builtin_amdgcn_mfma_f32_16x16x32_bf16(                             \
          __builtin_bit_cast(bf16x8,a_), __builtin_bit_cast(bf16x8,bw[1][ks]), A1,0,0,0); \
      A2 = __builtin_amdgcn_mfma_f32_16x16x32_bf16(                             \
          __builtin_bit_cast(bf16x8,a_), __builtin_bit_cast(bf16x8,bw[2][ks]), A2,0,0,0); \
      A3 = __builtin_amdgcn_mfma_f32_16x16x32_bf16(                             \
          __builtin_bit_cast(bf16x8,a_), __builtin_bit_cast(bf16x8,bw[3][ks]), A3,0,0,0); \
    } }

#define GATES(T, A0,A1,A2,A3, GB, CST, LR, ROWB, BO2, HSM, PB)                  \
  { _Pragma("unroll")                                                           \
    for (int r = 0; r < 4; ++r){                                                \
      if (jv && (T) < LR[r]){                                                   \
        float pi = A0[r] + bf2f(GB[r][0]);                                      \
        float pf = A1[r] + bf2f(GB[r][1]);                                      \
        float pg = A2[r] + bf2f(GB[r][2]);                                      \
        float po = A3[r] + bf2f(GB[r][3]);                                      \
        float ig = fsig2(pi), fg = fsig2(pf), g2 = ftanh2(pg), og = fsig2(po);  \
        float cc = fg*CST[r] + ig*g2;  CST[r] = cc;                             \
        float hn = og * ftanh2(L2E2 * cc);                                      \
        u16 hb = f2bf(hn);                                                      \
        HSM[(PB)^1][(hi*4+r)*168 + jj] = hb;                                    \
        if (!isL1){                                                             \
          int s_ = dir ? (LR[r]-1-(T)) : (T);                                   \
          h1[(size_t)(ROWB[r]+s_)*KSTR + dir*150 + jj] = hb;                    \
        } else {                                                                \
          bool isl = dir ? ((T)==0) : ((T)==LR[r]-1);                           \
          if (isl) lastf[(size_t)BO2[r]*304 + dir*150 + jj] = hn;               \
        }                                                                       \
      }                                                                         \
    } }

#define PREFT(GB, TT, LR, ROWB, TKS)                                            \
  { _Pragma("unroll")                                                           \
    for (int r = 0; r < 4; ++r){                                                \
      int Li = LR[r];                                                           \
      int tt = ((TT) < Li) ? (TT) : (Li-1);                                     \
      int s_ = dir ? (Li-1-tt) : tt;                                            \
      int rowi = isL1 ? (ROWB[r] + s_) : (int)TKS[(hi*4+r)*256 + s_];           \
      GB[r] = *(const u16x4*)(xg + (size_t)rowi*GSTR + jjc*4);                  \
    } }

#define REC_STEP(T, PB, GB0, GB1)                                               \
  { f32x4 aA0={0,0,0,0},aA1={0,0,0,0},aA2={0,0,0,0},aA3={0,0,0,0};              \
    f32x4 aB0={0,0,0,0},aB1={0,0,0,0},aB2={0,0,0,0},aB3={0,0,0,0};              \
    MFMA5(aA0,aA1,aA2,aA3, hsm0, PB)                                            \
    MFMA5(aB0,aB1,aB2,aB3, hsm1, PB)                                            \
    GATES(T, aA0,aA1,aA2,aA3, GB0, cst0, Lr0, rowb0, bo20, hsm0, PB)            \
    GATES(T, aB0,aB1,aB2,aB3, GB1, cst1, Lr1, rowb1, bo21, hsm1, PB)            \
    if ((T)+2 < maxL){                                                          \
      PREFT(GB0, (T)+2, Lr0, rowb0, tks0)                                       \
      PREFT(GB1, (T)+2, Lr1, rowb1, tks1)                                       \
    }                                                                           \
    __builtin_amdgcn_sched_barrier(0);                                          \
    asm volatile("s_waitcnt lgkmcnt(0)" ::: "memory");                          \
    __builtin_amdgcn_s_barrier();                                               \
    __builtin_amdgcn_sched_barrier(0);                                          \
  }

__launch_bounds__(640)
__global__ void k_recM(const u16* __restrict__ gF, const u16* __restrict__ gBf,
                       const u16* __restrict__ tF, const u16* __restrict__ tB,
                       const u16* __restrict__ Wh0F, const u16* __restrict__ Wh0B,
                       const u16* __restrict__ Wh1F, const u16* __restrict__ Wh1B,
                       const int* __restrict__ len, const int* __restrict__ perm,
                       const int* __restrict__ x,
                       u16* __restrict__ h1, float* __restrict__ lastf,
                       int coA, int coB, int mode0)
{
  const int isL1 = (blockIdx.z == 0) ? mode0 : 0;
  const int dir  = blockIdx.y;
  const int pr   = blockIdx.x;      // pair index: tiles 2pr, 2pr+1
  const int co   = isL1 ? coA : coB;
  const u16* xg  = isL1 ? (dir ? gBf : gF) : (dir ? tB : tF);
  const u16* Whh = isL1 ? (dir ? Wh1B : Wh1F) : (dir ? Wh0B : Wh0F);

  __shared__ u16 hsm0[2][16*168];
  __shared__ u16 hsm1[2][16*168];
  __shared__ u16 tks0[16*256];
  __shared__ u16 tks1[16*256];
  __shared__ int Ls[2][16], rbS[2][16], boS[2][16];

  int tid = threadIdx.x;
  int l = tid & 63, w = tid >> 6;     // w = jj-group 0..9
  int lo = l & 15, hi = l >> 4;
  int jj = w*16 + lo;                 // 0..159
  bool jv = (jj < HH);
  int jjc = jv ? jj : 0;

  // Whh B-fragments shared by both tiles: acc g covers rows g*150 + jj
  u16x8 bw[4][5];
  #pragma unroll
  for (int g = 0; g < 4; ++g)
    #pragma unroll
    for (int ks = 0; ks < 5; ++ks)
      bw[g][ks] = *(const u16x8*)(Whh + (size_t)(g*150 + jj)*WK + ks*32 + hi*8);

  for (int i = tid; i < 16*168; i += 640){
    hsm0[0][i] = 0; hsm0[1][i] = 0; hsm1[0][i] = 0; hsm1[1][i] = 0;
  }
  if (tid < 32){
    int tl = tid >> 4, i = tid & 15;
    int b = perm[co + (pr*2 + tl)*16 + i];
    Ls[tl][i]  = len[b];
    rbS[tl][i] = ((pr*2 + tl)*16 + i)*SS;
    boS[tl][i] = b;
  }
  __syncthreads();
  if (!isL1){
    for (int idx = tid; idx < 2*16*256; idx += 640){
      int tl = idx >> 12, rest = idx & 4095;
      u16 v = (u16)x[boS[tl][rest >> 8]*SS + (rest & 255)];
      if (tl == 0) tks0[rest] = v; else tks1[rest] = v;
    }
  }
  __syncthreads();

  int maxL = Ls[1][15];   // ascending sort -> tile 2pr+1 sample 15 longest
  int Lr0[4], rowb0[4], bo20[4], Lr1[4], rowb1[4], bo21[4];
  #pragma unroll
  for (int r = 0; r < 4; ++r){
    int i = hi*4 + r;
    Lr0[r] = Ls[0][i]; rowb0[r] = rbS[0][i]; bo20[r] = boS[0][i];
    Lr1[r] = Ls[1][i]; rowb1[r] = rbS[1][i]; bo21[r] = boS[1][i];
  }

  float cst0[4] = {0.f,0.f,0.f,0.f};
  float cst1[4] = {0.f,0.f,0.f,0.f};
  u16x4 gA0[4], gA1[4], gB0[4], gB1[4];
  PREFT(gA0, 0, Lr0, rowb0, tks0)
  PREFT(gA1, 0, Lr1, rowb1, tks1)
  PREFT(gB0, 1, Lr0, rowb0, tks0)
  PREFT(gB1, 1, Lr1, rowb1, tks1)

  for (int t = 0; t < maxL; t += 2){
    REC_STEP(t, 0, gA0, gA1)
    if (t + 1 < maxL){
      REC_STEP(t+1, 1, gB0, gB1)
    }
  }
}

// ---------------- classifier head (fp32, float4): out = tanh(last@W1.T+b1)@W2.T+b2 ----------------
__global__ void k_cls(const float* __restrict__ lastf,
                      const float* __restrict__ W1, const float* __restrict__ b1,
                      const float* __restrict__ W2, const float* __restrict__ b2,
                      float* __restrict__ out)
{
  __shared__ float inb[8][304];
  __shared__ float mid[8][304];
  int r0 = blockIdx.x * 8, tid = threadIdx.x;
  for (int i = tid; i < 8*76; i += 256){
    int r = i / 76, c4 = i - r*76;
    ((f4*)&inb[r][0])[c4] = ((const f4*)(lastf + (size_t)(r0+r)*304))[c4];
  }
  __syncthreads();
  for (int item = tid; item < 2400; item += 256){
    int r = item / 300, c = item - r*300;
    const f4* wr = (const f4*)(W1 + (size_t)c*300);
    const f4* xr = (const f4*)&inb[r][0];
    f4 a0 = {0,0,0,0}, a1 = {0,0,0,0}, a2 = {0,0,0,0};
    for (int k = 0; k < 75; k += 3){
      a0 += xr[k]   * wr[k];
      a1 += xr[k+1] * wr[k+1];
      a2 += xr[k+2] * wr[k+2];
    }
    f4 s4 = a0 + a1 + a2;
    float a = s4[0] + s4[1] + s4[2] + s4[3] + b1[c];
    mid[r][c] = 2.0f * __builtin_amdgcn_rcpf(1.0f + __builtin_amdgcn_exp2f(-L2E2*a)) - 1.0f;
  }
  __syncthreads();
  for (int item = tid; item < 2400; item += 256){
    int r = item / 300, c = item - r*300;
    const f4* wr = (const f4*)(W2 + (size_t)c*300);
    const f4* xr = (const f4*)&mid[r][0];
    f4 a0 = {0,0,0,0}, a1 = {0,0,0,0}, a2 = {0,0,0,0};
    for (int k = 0; k < 75; k += 3){
      a0 += xr[k]   * wr[k];
      a1 += xr[k+1] * wr[k+1];
      a2 += xr[k+2] * wr[k+2];
    }
    f4 s4 = a0 + a1 + a2;
    out[(size_t)(r0+r)*300 + c] = s4[0] + s4[1] + s4[2] + s4[3] + b2[c];
  }
}

extern "C" void kernel_launch(void* const* d_in, const int* in_sizes, int n_in,
                              void* d_out, int out_size, void* d_ws, size_t ws_size,
                              hipStream_t stream)
{
  const int*   x    = (const int*)d_in[0];
  const int*   mask = (const int*)d_in[1];
  const float* emb  = (const float*)d_in[2];
  const float* Wih[4] = {(const float*)d_in[3], (const float*)d_in[6],
                         (const float*)d_in[9], (const float*)d_in[12]};
  const float* Whh[4] = {(const float*)d_in[4], (const float*)d_in[7],
                         (const float*)d_in[10], (const float*)d_in[13]};
  const float* bs[4]  = {(const float*)d_in[5], (const float*)d_in[8],
                         (const float*)d_in[11], (const float*)d_in[14]};
  const float* W1 = (const float*)d_in[15];
  const float* b1 = (const float*)d_in[16];
  const float* W2 = (const float*)d_in[17];
  const float* b2 = (const float*)d_in[18];
  float* out = (float*)d_out;

  char* p = (char*)d_ws;
  auto alloc = [&](size_t bytes){ char* r = p; p += (bytes + 255) & ~(size_t)255; return r; };

  // fixed allocations (~70 MB incl. token->gate tables)
  u16 *WihP[4], *WhhP[4];
  for (int i = 0; i < 4; ++i){
    WihP[i] = (u16*)alloc(640*320*2);
    WhhP[i] = (u16*)alloc(640*160*2);
  }
  float* biasP[4];
  for (int i = 0; i < 4; ++i) biasP[i] = (float*)alloc(640*4);
  int* len  = (int*)alloc(1024*4);
  int* perm = (int*)alloc(1024*4);
  float* lastf = (float*)alloc((size_t)1024*304*4);
  u16* embP = (u16*)alloc((size_t)VPAD*KSTR*2);
  u16* tabF = (u16*)alloc((size_t)VPAD*GSTR*2);
  u16* tabB = (u16*)alloc((size_t)VPAD*GSTR*2);
  size_t fixed_end = (size_t)(p - (char*)d_ws);

  // variable: h1 (chunk) + TWO single-chunk gate buffers (both dirs)
  const size_t per_sample = (size_t)SS*KSTR*2 + 2*(size_t)SS*GSTR*2;  // 778240 B
  int nc = 32;
  const int cands[6] = {1, 2, 4, 8, 16, 32};
  for (int ci = 0; ci < 6; ++ci){
    size_t need = fixed_end + (size_t)(BB / cands[ci]) * per_sample + (1u<<20);
    if (need <= ws_size){ nc = cands[ci]; break; }
  }
  const int Bc = BB / nc;
  const int Mc = Bc * SS;

  u16* h1    = (u16*)alloc((size_t)Mc*KSTR*2);
  u16* gateF = (u16*)alloc((size_t)Mc*GSTR*2);
  u16* gateB = (u16*)alloc((size_t)Mc*GSTR*2);

  hipMemsetAsync(h1, 0, (size_t)Mc*KSTR*2, stream);   // pad cols 300..319 must be 0

  k_len <<<dim3(1024), dim3(256), 0, stream>>>(mask, len);
  k_sort<<<dim3(1),    dim3(1024),0, stream>>>(len, perm);

  PrepW pw;
  for (int i = 0; i < 4; ++i){
    pw.src[i] = Wih[i]; pw.dst[i] = WihP[i];
    pw.R[i] = GG; pw.C[i] = DD; pw.DR[i] = 640; pw.DC[i] = KSTR;
    pw.src[4+i] = Whh[i]; pw.dst[4+i] = WhhP[i];
    pw.R[4+i] = GG; pw.C[4+i] = HH; pw.DR[4+i] = 640; pw.DC[4+i] = WK;
  }
  k_prepw<<<dim3(800, 8), dim3(256), 0, stream>>>(pw);

  PrepB pb;
  for (int i = 0; i < 4; ++i){ pb.src[i] = bs[i]; pb.dst[i] = biasP[i]; }
  k_prepb<<<dim3(3, 4), dim3(256), 0, stream>>>(pb);

  k_prepemb<<<dim3((VPAD*KSTR + 255)/256), dim3(256), 0, stream>>>(emb, embP);

  // token -> layer-0 x-gate tables (both dirs), bias folded, interleaved layout
  k_gemm<<<dim3(VPAD/128, 2, 2), dim3(512), 0, stream>>>(embP, WihP[0], WihP[1],
                                                         biasP[0], biasP[1], tabF, tabB);

  // chained pipeline: L0(c0) | G(c0) | [L1(c)+L0(c+1)] G(c+1) ... | L1(last)
  k_recM<<<dim3(Bc/32, 2, 1), dim3(640), 0, stream>>>(gateF, gateB, tabF, tabB,
                                                      WhhP[0], WhhP[1], WhhP[2], WhhP[3],
                                                      len, perm, x, h1, lastf,
                                                      0, 0, /*mode0=*/0);
  k_gemm<<<dim3(Mc/128, 2, 2), dim3(512), 0, stream>>>(h1, WihP[2], WihP[3],
                                                       biasP[2], biasP[3], gateF, gateB);
  for (int c = 0; c < nc; ++c){
    if (c + 1 < nc){
      k_recM<<<dim3(Bc/32, 2, 2), dim3(640), 0, stream>>>(gateF, gateB, tabF, tabB,
                                                          WhhP[0], WhhP[1], WhhP[2], WhhP[3],
                                                          len, perm, x, h1, lastf,
                                                          c*Bc, (c+1)*Bc, /*mode0=*/1);
      k_gemm<<<dim3(Mc/128, 2, 2), dim3(512), 0, stream>>>(h1, WihP[2], WihP[3],
                                                           biasP[2], biasP[3], gateF, gateB);
    } else {
      k_recM<<<dim3(Bc/32, 2, 1), dim3(640), 0, stream>>>(gateF, gateB, tabF, tabB,
                                                          WhhP[0], WhhP[1], WhhP[2], WhhP[3],
                                                          len, perm, x, h1, lastf,
                                                          c*Bc, 0, /*mode0=*/1);
    }
  }

  k_cls<<<dim3(128), dim3(256), 0, stream>>>(lastf, W1, b1, W2, b2, out);
}

// Round 10
// 6322.289 us; speedup vs baseline: 1.5344x; 1.5344x over previous
//
#include <hip/hip_runtime.h>

typedef unsigned short u16;
typedef __bf16 bf16x8 __attribute__((ext_vector_type(8)));
typedef float f32x4 __attribute__((ext_vector_type(4)));
typedef float f4 __attribute__((ext_vector_type(4)));
typedef unsigned short u16x8 __attribute__((ext_vector_type(8)));
typedef unsigned short u16x4 __attribute__((ext_vector_type(4)));

#define BB 1024
#define SS 256
#define DD 300
#define HH 150
#define GG 600
#define VV 21257
#define VPAD 21376      // 167*128
#define KSTR 320        // padded K stride for h1 / emb table
#define GSTR 600        // gate row stride (u16), layout [jj][4 gates] interleaved
#define WK 160          // padded Whh K stride
#define L2E 1.442695041f
#define L2E2 2.885390082f

static __device__ __forceinline__ float bf2f(u16 u){
  unsigned v = ((unsigned)u) << 16;
  return __builtin_bit_cast(float, v);
}
static __device__ __forceinline__ u16 f2bf(float f){
  unsigned u = __builtin_bit_cast(unsigned, f);
  u = u + 0x7FFFu + ((u >> 16) & 1u);
  return (u16)(u >> 16);
}
// inputs PRE-SCALED by log2e (sig) / 2log2e (tanh)
static __device__ __forceinline__ float fsig2(float p){
  return __builtin_amdgcn_rcpf(1.0f + __builtin_amdgcn_exp2f(-p));
}
static __device__ __forceinline__ float ftanh2(float p){
  return 2.0f * __builtin_amdgcn_rcpf(1.0f + __builtin_amdgcn_exp2f(-p)) - 1.0f;
}

// ---------------- lengths from mask ----------------
__global__ void k_len(const int* __restrict__ mask, int* __restrict__ len){
  __shared__ int red[256];
  int b = blockIdx.x, t = threadIdx.x;
  red[t] = (mask[b*SS + t] != 0) ? 1 : 0;
  __syncthreads();
  for (int o = 128; o > 0; o >>= 1){
    if (t < o) red[t] += red[t+o];
    __syncthreads();
  }
  if (t == 0) len[b] = red[0];
}

// ---------------- deterministic rank sort by length (ascending) ----------------
__global__ void k_sort(const int* __restrict__ len, int* __restrict__ perm){
  __shared__ int L[1024];
  int b = threadIdx.x;
  int l = len[b];
  L[b] = l;
  __syncthreads();
  int r = 0;
  for (int j = 0; j < 1024; ++j){
    int lj = L[j];
    r += (lj < l) || (lj == l && j < b);
  }
  perm[r] = b;
}

// ---------------- weight pad/convert f32 -> bf16, gate-row pre-scale by log2e ----------------
struct PrepW {
  const float* src[8];
  u16* dst[8];
  int R[8], C[8], DR[8], DC[8];
};
__global__ void k_prepw(PrepW p){
  int z = blockIdx.y;
  int n = p.DR[z]*p.DC[z];
  for (int i = blockIdx.x*256 + threadIdx.x; i < n; i += 800*256){
    int r = i / p.DC[z], c = i - r*p.DC[z];
    float v = (r < p.R[z] && c < p.C[z]) ? p.src[z][r*p.C[z] + c] : 0.f;
    float sc = (r >= 300 && r < 450) ? L2E2 : L2E;   // g-gate rows get 2*log2e
    p.dst[z][i] = f2bf(v * sc);
  }
}
struct PrepB { const float* src[4]; float* dst[4]; };
__global__ void k_prepb(PrepB p){
  int z = blockIdx.y;
  int i = blockIdx.x*256 + threadIdx.x;
  if (i < 640){
    float v = (i < GG) ? p.src[z][i] : 0.f;
    float sc = (i >= 300 && i < 450) ? L2E2 : L2E;
    p.dst[z][i] = v * sc;
  }
}

// ---------------- embedding table pad/convert: [VPAD][KSTR] bf16, row 0 zeroed ----------------
__global__ void k_prepemb(const float* __restrict__ emb, u16* __restrict__ dst){
  long i = (long)blockIdx.x*256 + threadIdx.x;
  if (i >= (long)VPAD*KSTR) return;
  int r = (int)(i / KSTR), c = (int)(i - (long)r*KSTR);
  float v = (r >= 1 && r < VV && c < DD) ? emb[(size_t)r*DD + c] : 0.f;
  dst[i] = f2bf(v);
}

// ---------------- register-fragment GEMM: no LDS, no barriers ----------------
__launch_bounds__(512, 2)
__global__ void k_gemm(const u16* __restrict__ A,
                       const u16* __restrict__ Wf, const u16* __restrict__ Wb,
                       const float* __restrict__ bsf, const float* __restrict__ bsb,
                       u16* __restrict__ of, u16* __restrict__ ob)
{
  const u16* W = blockIdx.z ? Wb : Wf;
  const float* bias = blockIdx.z ? bsb : bsf;
  u16* outp = blockIdx.z ? ob : of;

  int tid = threadIdx.x;
  int l = tid & 63, w = tid >> 6;
  int lo = l & 15, hi = l >> 4;
  int wm = w >> 2, wn = w & 3;
  int m0 = blockIdx.x * 128;
  int n0 = blockIdx.y * 320;

  const u16* Abase = A + (size_t)(m0 + wm*64 + lo)*KSTR + hi*8;
  const u16* Bbase = W + (size_t)(n0 + wn*80 + lo)*KSTR + hi*8;

  u16x8 avA[4], bvA[5], avB[4], bvB[5];
  #pragma unroll
  for (int mt = 0; mt < 4; ++mt) avA[mt] = *(const u16x8*)(Abase + (size_t)mt*16*KSTR);
  #pragma unroll
  for (int nt = 0; nt < 5; ++nt) bvA[nt] = *(const u16x8*)(Bbase + (size_t)nt*16*KSTR);

  f32x4 acc[4][5];
  #pragma unroll
  for (int a = 0; a < 4; ++a)
    #pragma unroll
    for (int b = 0; b < 5; ++b) acc[a][b] = (f32x4){0.f,0.f,0.f,0.f};

  for (int kk = 0; kk < 10; kk += 2){
    {
      int kc = (kk+1)*32;
      #pragma unroll
      for (int mt = 0; mt < 4; ++mt) avB[mt] = *(const u16x8*)(Abase + (size_t)mt*16*KSTR + kc);
      #pragma unroll
      for (int nt = 0; nt < 5; ++nt) bvB[nt] = *(const u16x8*)(Bbase + (size_t)nt*16*KSTR + kc);
    }
    #pragma unroll
    for (int mt = 0; mt < 4; ++mt)
      #pragma unroll
      for (int nt = 0; nt < 5; ++nt)
        acc[mt][nt] = __builtin_amdgcn_mfma_f32_16x16x32_bf16(
            __builtin_bit_cast(bf16x8, avA[mt]),
            __builtin_bit_cast(bf16x8, bvA[nt]),
            acc[mt][nt], 0, 0, 0);
    if (kk + 2 < 10){
      int kc = (kk+2)*32;
      #pragma unroll
      for (int mt = 0; mt < 4; ++mt) avA[mt] = *(const u16x8*)(Abase + (size_t)mt*16*KSTR + kc);
      #pragma unroll
      for (int nt = 0; nt < 5; ++nt) bvA[nt] = *(const u16x8*)(Bbase + (size_t)nt*16*KSTR + kc);
    }
    #pragma unroll
    for (int mt = 0; mt < 4; ++mt)
      #pragma unroll
      for (int nt = 0; nt < 5; ++nt)
        acc[mt][nt] = __builtin_amdgcn_mfma_f32_16x16x32_bf16(
            __builtin_bit_cast(bf16x8, avB[mt]),
            __builtin_bit_cast(bf16x8, bvB[nt]),
            acc[mt][nt], 0, 0, 0);
  }

  #pragma unroll
  for (int mt = 0; mt < 4; ++mt){
    #pragma unroll
    for (int nt = 0; nt < 5; ++nt){
      int col = n0 + wn*80 + nt*16 + lo;
      if (col < GG){
        float bsv = bias[col];
        int g = (col >= 450) ? 3 : (col >= 300) ? 2 : (col >= 150) ? 1 : 0;
        int cofs = (col - g*150)*4 + g;   // interleaved [jj][gate]
        #pragma unroll
        for (int r = 0; r < 4; ++r){
          int row = m0 + wm*64 + mt*16 + hi*4 + r;
          outp[(size_t)row*GSTR + cofs] = f2bf(acc[mt][nt][r] + bsv);
        }
      }
    }
  }
}

// ---------------- merged recurrence (round-6 verbatim): single 16-sample tile per WG ----------------
#define PREF(GB, TT)                                                            \
  {                                                                             \
    _Pragma("unroll")                                                           \
    for (int r = 0; r < 4; ++r){                                                \
      int Li = Lr[r];                                                           \
      int tt = ((TT) < Li) ? (TT) : (Li-1);                                     \
      int s_ = dir ? (Li-1-tt) : tt;                                            \
      int rowi;                                                                 \
      if (isL1) rowi = rowb[r] + s_;                                            \
      else      rowi = (int)tks[(hi*4+r)*256 + s_];                             \
      GB[r] = *(const u16x4*)(xg + (size_t)rowi*GSTR + jjc*4);                  \
    }                                                                           \
  }

#define REC_STEP(T, PB, GB)                                                     \
  {                                                                             \
    f32x4 acc0 = {0,0,0,0}, acc1 = {0,0,0,0}, acc2 = {0,0,0,0}, acc3 = {0,0,0,0}; \
    _Pragma("unroll")                                                           \
    for (int ks = 0; ks < 5; ++ks){                                             \
      u16x8 a_ = *(const u16x8*)&hsm[PB][lo*168 + ks*32 + hi*8];                \
      acc0 = __builtin_amdgcn_mfma_f32_16x16x32_bf16(                           \
          __builtin_bit_cast(bf16x8, a_), __builtin_bit_cast(bf16x8, bw[0][ks]), acc0, 0,0,0); \
      acc1 = __builtin_amdgcn_mfma_f32_16x16x32_bf16(                           \
          __builtin_bit_cast(bf16x8, a_), __builtin_bit_cast(bf16x8, bw[1][ks]), acc1, 0,0,0); \
      acc2 = __builtin_amdgcn_mfma_f32_16x16x32_bf16(                           \
          __builtin_bit_cast(bf16x8, a_), __builtin_bit_cast(bf16x8, bw[2][ks]), acc2, 0,0,0); \
      acc3 = __builtin_amdgcn_mfma_f32_16x16x32_bf16(                           \
          __builtin_bit_cast(bf16x8, a_), __builtin_bit_cast(bf16x8, bw[3][ks]), acc3, 0,0,0); \
    }                                                                           \
    _Pragma("unroll")                                                           \
    for (int r = 0; r < 4; ++r){                                                \
      if (jv && (T) < Lr[r]){                                                   \
        float pi = acc0[r] + bf2f(GB[r][0]);                                    \
        float pf = acc1[r] + bf2f(GB[r][1]);                                    \
        float pg = acc2[r] + bf2f(GB[r][2]);                                    \
        float po = acc3[r] + bf2f(GB[r][3]);                                    \
        float ig = fsig2(pi), fg = fsig2(pf), g2 = ftanh2(pg), og = fsig2(po);  \
        float cc = fg*cst[r] + ig*g2;  cst[r] = cc;                             \
        float hn = og * ftanh2(L2E2 * cc);                                      \
        u16 hb = f2bf(hn);                                                      \
        hsm[(PB)^1][(hi*4+r)*168 + jj] = hb;                                    \
        if (!isL1){                                                             \
          int s_ = dir ? (Lr[r]-1-(T)) : (T);                                   \
          h1[(size_t)(rowb[r]+s_)*KSTR + dir*150 + jj] = hb;                    \
        } else {                                                                \
          bool isl = dir ? ((T)==0) : ((T)==Lr[r]-1);                           \
          if (isl) lastf[(size_t)bo2[r]*304 + dir*150 + jj] = hn;               \
        }                                                                       \
      }                                                                         \
    }                                                                           \
    if ((T)+4 < maxL){                                                          \
      PREF(GB, (T)+4)                                                           \
    }                                                                           \
    __builtin_amdgcn_sched_barrier(0);                                          \
    asm volatile("s_waitcnt lgkmcnt(0)" ::: "memory");                          \
    __builtin_amdgcn_s_barrier();                                               \
    __builtin_amdgcn_sched_barrier(0);                                          \
  }

__launch_bounds__(640, 2)
__global__ void k_recM(const u16* __restrict__ gF, const u16* __restrict__ gBf,
                       const u16* __restrict__ tF, const u16* __restrict__ tB,
                       const u16* __restrict__ Wh0F, const u16* __restrict__ Wh0B,
                       const u16* __restrict__ Wh1F, const u16* __restrict__ Wh1B,
                       const int* __restrict__ len, const int* __restrict__ perm,
                       const int* __restrict__ x,
                       u16* __restrict__ h1, float* __restrict__ lastf,
                       int coA, int coB, int mode0)
{
  const int isL1 = (blockIdx.z == 0) ? mode0 : 0;
  const int dir  = blockIdx.y;
  const int tile = blockIdx.x;
  const int co   = isL1 ? coA : coB;
  const u16* xg  = isL1 ? (dir ? gBf : gF) : (dir ? tB : tF);
  const u16* Whh = isL1 ? (dir ? Wh1B : Wh1F) : (dir ? Wh0B : Wh0F);

  __shared__ u16 hsm[2][16*168];
  __shared__ u16 tks[16*256];
  __shared__ int Ls[16], rbL[16], boS[16];

  int tid = threadIdx.x;
  int l = tid & 63, w = tid >> 6;
  int lo = l & 15, hi = l >> 4;
  int jj = w*16 + lo;
  bool jv = (jj < HH);
  int jjc = jv ? jj : 0;

  u16x8 bw[4][5];
  #pragma unroll
  for (int g = 0; g < 4; ++g)
    #pragma unroll
    for (int ks = 0; ks < 5; ++ks)
      bw[g][ks] = *(const u16x8*)(Whh + (size_t)(g*150 + jj)*WK + ks*32 + hi*8);

  for (int i = tid; i < 2*16*168; i += 640) ((u16*)hsm)[i] = 0;
  if (tid < 16){
    int b = perm[co + tile*16 + tid];
    Ls[tid]  = len[b];
    rbL[tid] = (tile*16 + tid)*SS;
    boS[tid] = b;
  }
  __syncthreads();
  if (!isL1){
    for (int idx = tid; idx < 16*256; idx += 640){
      int i = idx >> 8, s = idx & 255;
      tks[idx] = (u16)x[boS[i]*SS + s];
    }
  }
  __syncthreads();

  int maxL = Ls[15];
  int Lr[4], rowb[4], bo2[4];
  #pragma unroll
  for (int r = 0; r < 4; ++r){
    int i = hi*4 + r;
    Lr[r] = Ls[i]; rowb[r] = rbL[i]; bo2[r] = boS[i];
  }

  float cst[4] = {0.f, 0.f, 0.f, 0.f};
  u16x4 g0[4], g1[4], g2b[4], g3[4];
  PREF(g0, 0)
  PREF(g1, 1)
  PREF(g2b, 2)
  PREF(g3, 3)

  for (int t = 0; t < maxL; t += 4){
    REC_STEP(t, 0, g0)
    if (t + 1 < maxL) REC_STEP(t+1, 1, g1)
    if (t + 2 < maxL) REC_STEP(t+2, 0, g2b)
    if (t + 3 < maxL) REC_STEP(t+3, 1, g3)
  }
}

// ---------------- diagnostic probes: recurrence-step replica with component ablation ----------------
// MODE bits: 1=MFMA, 2=gate-loads, 4=trans(sig/tanh), 8=barrier, 16=h1-stores
#define PPREF(GB, TT)                                                           \
  { _Pragma("unroll")                                                           \
    for (int r = 0; r < 4; ++r){                                                \
      int s_ = (TT) & 255;                                                      \
      GB[r] = *(const u16x4*)(xg + (size_t)(prow[r]+s_)*GSTR + jjc*4);          \
    } }

#define PSTEP(T, PB, GB)                                                        \
  { f32x4 a0={0,0,0,0},a1={0,0,0,0},a2={0,0,0,0},a3={0,0,0,0};                  \
    if (MODE & 1){                                                              \
      _Pragma("unroll")                                                         \
      for (int ks = 0; ks < 5; ++ks){                                           \
        u16x8 a_ = *(const u16x8*)&hsm[PB][lo*168 + ks*32 + hi*8];              \
        a0 = __builtin_amdgcn_mfma_f32_16x16x32_bf16(                           \
            __builtin_bit_cast(bf16x8,a_), __builtin_bit_cast(bf16x8,bw[0][ks]), a0,0,0,0); \
        a1 = __builtin_amdgcn_mfma_f32_16x16x32_bf16(                           \
            __builtin_bit_cast(bf16x8,a_), __builtin_bit_cast(bf16x8,bw[1][ks]), a1,0,0,0); \
        a2 = __builtin_amdgcn_mfma_f32_16x16x32_bf16(                           \
            __builtin_bit_cast(bf16x8,a_), __builtin_bit_cast(bf16x8,bw[2][ks]), a2,0,0,0); \
        a3 = __builtin_amdgcn_mfma_f32_16x16x32_bf16(                           \
            __builtin_bit_cast(bf16x8,a_), __builtin_bit_cast(bf16x8,bw[3][ks]), a3,0,0,0); \
      }                                                                         \
    } else {                                                                    \
      _Pragma("unroll")                                                         \
      for (int ks = 0; ks < 5; ++ks){                                           \
        u16x8 a_ = *(const u16x8*)&hsm[PB][lo*168 + ks*32 + hi*8];              \
        asm volatile("" :: "v"(a_));                                            \
      }                                                                         \
      a0[0]=cst[0]; a0[1]=cst[1]; a0[2]=cst[2]; a0[3]=cst[3];                   \
      a1 = a0; a2 = a0; a3 = a0;                                                \
    }                                                                           \
    _Pragma("unroll")                                                           \
    for (int r = 0; r < 4; ++r){                                                \
      if (jv){                                                                  \
        float pi = a0[r] + bf2f(GB[r][0]);                                      \
        float pf = a1[r] + bf2f(GB[r][1]);                                      \
        float pg = a2[r] + bf2f(GB[r][2]);                                      \
        float po = a3[r] + bf2f(GB[r][3]);                                      \
        float ig, fg, g2, og;                                                   \
        if (MODE & 4){ ig=fsig2(pi); fg=fsig2(pf); g2=ftanh2(pg); og=fsig2(po);}\
        else { ig=pi*0.25f; fg=pf*0.25f; g2=pg*0.25f; og=po*0.25f; }            \
        float cc = fg*cst[r] + ig*g2;  cst[r] = cc;                             \
        float hn = (MODE & 4) ? og*ftanh2(L2E2*cc) : og*cc;                     \
        u16 hb = f2bf(hn);                                                      \
        hsm[(PB)^1][(hi*4+r)*168 + jj] = hb;                                    \
        if (MODE & 16){                                                         \
          int s_ = (T) & 255;                                                   \
          h1d[(size_t)(prow[r]+s_)*KSTR + jj] = hb;                             \
        }                                                                       \
      }                                                                         \
    }                                                                           \
    if (MODE & 2){ if ((T)+4 < 256){ PPREF(GB, (T)+4) } }                       \
    else { asm volatile("" : "+v"(GB[0]), "+v"(GB[1]), "+v"(GB[2]), "+v"(GB[3])); } \
    if (MODE & 8){                                                              \
      __builtin_amdgcn_sched_barrier(0);                                        \
      asm volatile("s_waitcnt lgkmcnt(0)" ::: "memory");                        \
      __builtin_amdgcn_s_barrier();                                             \
      __builtin_amdgcn_sched_barrier(0);                                        \
    } else {                                                                    \
      asm volatile("s_waitcnt lgkmcnt(0)" ::: "memory");                        \
    }                                                                           \
  }

template<int MODE>
__launch_bounds__(640, 2)
__global__ void k_probe(const u16* __restrict__ xg, const u16* __restrict__ Whh,
                        u16* __restrict__ h1d, u16* __restrict__ sink)
{
  __shared__ u16 hsm[2][16*168];
  int tid = threadIdx.x;
  int l = tid & 63, w = tid >> 6;
  int lo = l & 15, hi = l >> 4;
  int jj = w*16 + lo;
  bool jv = (jj < HH);
  int jjc = jv ? jj : 0;

  u16x8 bw[4][5];
  #pragma unroll
  for (int g = 0; g < 4; ++g)
    #pragma unroll
    for (int ks = 0; ks < 5; ++ks)
      bw[g][ks] = *(const u16x8*)(Whh + (size_t)(g*150 + jj)*WK + ks*32 + hi*8);

  for (int i = tid; i < 2*16*168; i += 640) ((u16*)hsm)[i] = 0;
  __syncthreads();

  int prow[4];
  #pragma unroll
  for (int r = 0; r < 4; ++r)
    prow[r] = ((blockIdx.x & 31)*16 + hi*4 + r) * 256;

  float cst[4] = {0.f,0.f,0.f,0.f};
  u16x4 g0[4], g1[4], g2b[4], g3[4];
  PPREF(g0, 0)
  PPREF(g1, 1)
  PPREF(g2b, 2)
  PPREF(g3, 3)

  for (int t = 0; t < 256; t += 4){
    PSTEP(t, 0, g0)
    PSTEP(t+1, 1, g1)
    PSTEP(t+2, 0, g2b)
    PSTEP(t+3, 1, g3)
  }
  if (tid < 64) sink[blockIdx.x*64 + tid] = f2bf(cst[0]+cst[1]+cst[2]+cst[3]);
}

// ---------------- classifier head (fp32, float4) ----------------
__global__ void k_cls(const float* __restrict__ lastf,
                      const float* __restrict__ W1, const float* __restrict__ b1,
                      const float* __restrict__ W2, const float* __restrict__ b2,
                      float* __restrict__ out)
{
  __shared__ float inb[8][304];
  __shared__ float mid[8][304];
  int r0 = blockIdx.x * 8, tid = threadIdx.x;
  for (int i = tid; i < 8*76; i += 256){
    int r = i / 76, c4 = i - r*76;
    ((f4*)&inb[r][0])[c4] = ((const f4*)(lastf + (size_t)(r0+r)*304))[c4];
  }
  __syncthreads();
  for (int item = tid; item < 2400; item += 256){
    int r = item / 300, c = item - r*300;
    const f4* wr = (const f4*)(W1 + (size_t)c*300);
    const f4* xr = (const f4*)&inb[r][0];
    f4 a0 = {0,0,0,0}, a1 = {0,0,0,0}, a2 = {0,0,0,0};
    for (int k = 0; k < 75; k += 3){
      a0 += xr[k]   * wr[k];
      a1 += xr[k+1] * wr[k+1];
      a2 += xr[k+2] * wr[k+2];
    }
    f4 s4 = a0 + a1 + a2;
    float a = s4[0] + s4[1] + s4[2] + s4[3] + b1[c];
    mid[r][c] = 2.0f * __builtin_amdgcn_rcpf(1.0f + __builtin_amdgcn_exp2f(-L2E2*a)) - 1.0f;
  }
  __syncthreads();
  for (int item = tid; item < 2400; item += 256){
    int r = item / 300, c = item - r*300;
    const f4* wr = (const f4*)(W2 + (size_t)c*300);
    const f4* xr = (const f4*)&mid[r][0];
    f4 a0 = {0,0,0,0}, a1 = {0,0,0,0}, a2 = {0,0,0,0};
    for (int k = 0; k < 75; k += 3){
      a0 += xr[k]   * wr[k];
      a1 += xr[k+1] * wr[k+1];
      a2 += xr[k+2] * wr[k+2];
    }
    f4 s4 = a0 + a1 + a2;
    out[(size_t)(r0+r)*300 + c] = s4[0] + s4[1] + s4[2] + s4[3] + b2[c];
  }
}

extern "C" void kernel_launch(void* const* d_in, const int* in_sizes, int n_in,
                              void* d_out, int out_size, void* d_ws, size_t ws_size,
                              hipStream_t stream)
{
  const int*   x    = (const int*)d_in[0];
  const int*   mask = (const int*)d_in[1];
  const float* emb  = (const float*)d_in[2];
  const float* Wih[4] = {(const float*)d_in[3], (const float*)d_in[6],
                         (const float*)d_in[9], (const float*)d_in[12]};
  const float* Whh[4] = {(const float*)d_in[4], (const float*)d_in[7],
                         (const float*)d_in[10], (const float*)d_in[13]};
  const float* bs[4]  = {(const float*)d_in[5], (const float*)d_in[8],
                         (const float*)d_in[11], (const float*)d_in[14]};
  const float* W1 = (const float*)d_in[15];
  const float* b1 = (const float*)d_in[16];
  const float* W2 = (const float*)d_in[17];
  const float* b2 = (const float*)d_in[18];
  float* out = (float*)d_out;

  char* p = (char*)d_ws;
  auto alloc = [&](size_t bytes){ char* r = p; p += (bytes + 255) & ~(size_t)255; return r; };

  u16 *WihP[4], *WhhP[4];
  for (int i = 0; i < 4; ++i){
    WihP[i] = (u16*)alloc(640*320*2);
    WhhP[i] = (u16*)alloc(640*160*2);
  }
  float* biasP[4];
  for (int i = 0; i < 4; ++i) biasP[i] = (float*)alloc(640*4);
  int* len  = (int*)alloc(1024*4);
  int* perm = (int*)alloc(1024*4);
  float* lastf = (float*)alloc((size_t)1024*304*4);
  u16* embP = (u16*)alloc((size_t)VPAD*KSTR*2);
  u16* tabF = (u16*)alloc((size_t)VPAD*GSTR*2);
  u16* tabB = (u16*)alloc((size_t)VPAD*GSTR*2);
  u16* psink = (u16*)alloc(128*64*2);
  size_t fixed_end = (size_t)(p - (char*)d_ws);

  const size_t per_sample = (size_t)SS*KSTR*2 + 2*(size_t)SS*GSTR*2;  // 778240 B
  int nc = 32;
  const int cands[6] = {1, 2, 4, 8, 16, 32};
  for (int ci = 0; ci < 6; ++ci){
    size_t need = fixed_end + (size_t)(BB / cands[ci]) * per_sample + (1u<<20);
    if (need <= ws_size){ nc = cands[ci]; break; }
  }
  const int Bc = BB / nc;
  const int Mc = Bc * SS;

  u16* h1    = (u16*)alloc((size_t)Mc*KSTR*2);
  u16* gateF = (u16*)alloc((size_t)Mc*GSTR*2);
  u16* gateB = (u16*)alloc((size_t)Mc*GSTR*2);

  hipMemsetAsync(h1, 0, (size_t)Mc*KSTR*2, stream);

  k_len <<<dim3(1024), dim3(256), 0, stream>>>(mask, len);
  k_sort<<<dim3(1),    dim3(1024),0, stream>>>(len, perm);

  PrepW pw;
  for (int i = 0; i < 4; ++i){
    pw.src[i] = Wih[i]; pw.dst[i] = WihP[i];
    pw.R[i] = GG; pw.C[i] = DD; pw.DR[i] = 640; pw.DC[i] = KSTR;
    pw.src[4+i] = Whh[i]; pw.dst[4+i] = WhhP[i];
    pw.R[4+i] = GG; pw.C[4+i] = HH; pw.DR[4+i] = 640; pw.DC[4+i] = WK;
  }
  k_prepw<<<dim3(800, 8), dim3(256), 0, stream>>>(pw);

  PrepB pb;
  for (int i = 0; i < 4; ++i){ pb.src[i] = bs[i]; pb.dst[i] = biasP[i]; }
  k_prepb<<<dim3(3, 4), dim3(256), 0, stream>>>(pb);

  k_prepemb<<<dim3((VPAD*KSTR + 255)/256), dim3(256), 0, stream>>>(emb, embP);

  k_gemm<<<dim3(VPAD/128, 2, 2), dim3(512), 0, stream>>>(embP, WihP[0], WihP[1],
                                                         biasP[0], biasP[1], tabF, tabB);

  k_recM<<<dim3(Bc/16, 2, 1), dim3(640), 0, stream>>>(gateF, gateB, tabF, tabB,
                                                      WhhP[0], WhhP[1], WhhP[2], WhhP[3],
                                                      len, perm, x, h1, lastf,
                                                      0, 0, /*mode0=*/0);
  k_gemm<<<dim3(Mc/128, 2, 2), dim3(512), 0, stream>>>(h1, WihP[2], WihP[3],
                                                       biasP[2], biasP[3], gateF, gateB);
  for (int c = 0; c < nc; ++c){
    if (c + 1 < nc){
      k_recM<<<dim3(Bc/16, 2, 2), dim3(640), 0, stream>>>(gateF, gateB, tabF, tabB,
                                                          WhhP[0], WhhP[1], WhhP[2], WhhP[3],
                                                          len, perm, x, h1, lastf,
                                                          c*Bc, (c+1)*Bc, /*mode0=*/1);
      k_gemm<<<dim3(Mc/128, 2, 2), dim3(512), 0, stream>>>(h1, WihP[2], WihP[3],
                                                           biasP[2], biasP[3], gateF, gateB);
    } else {
      k_recM<<<dim3(Bc/16, 2, 1), dim3(640), 0, stream>>>(gateF, gateB, tabF, tabB,
                                                          WhhP[0], WhhP[1], WhhP[2], WhhP[3],
                                                          len, perm, x, h1, lastf,
                                                          c*Bc, 0, /*mode0=*/1);
    }
  }

  k_cls<<<dim3(128), dim3(256), 0, stream>>>(lastf, W1, b1, W2, b2, out);

  // ---- diagnostic probes (write only to dead ws scratch; timings read via rocprof) ----
  k_probe<31><<<dim3(128), dim3(640), 0, stream>>>(gateF, WhhP[2], h1, psink);  // full
  k_probe<30><<<dim3(128), dim3(640), 0, stream>>>(gateF, WhhP[2], h1, psink);  // -MFMA
  k_probe<29><<<dim3(128), dim3(640), 0, stream>>>(gateF, WhhP[2], h1, psink);  // -gate loads
  k_probe<27><<<dim3(128), dim3(640), 0, stream>>>(gateF, WhhP[2], h1, psink);  // -trans
  k_probe<23><<<dim3(128), dim3(640), 0, stream>>>(gateF, WhhP[2], h1, psink);  // -barrier
  k_probe<15><<<dim3(128), dim3(640), 0, stream>>>(gateF, WhhP[2], h1, psink);  // -stores
}

// Round 12
// 5945.373 us; speedup vs baseline: 1.6316x; 1.0634x over previous
//
#include <hip/hip_runtime.h>

typedef unsigned short u16;
typedef __bf16 bf16x8 __attribute__((ext_vector_type(8)));
typedef float f32x4 __attribute__((ext_vector_type(4)));
typedef float f4 __attribute__((ext_vector_type(4)));
typedef unsigned short u16x8 __attribute__((ext_vector_type(8)));
typedef unsigned short u16x4 __attribute__((ext_vector_type(4)));

#define BB 1024
#define SS 256
#define DD 300
#define HH 150
#define GG 600
#define VV 21257
#define VPAD 21376      // 167*128
#define KSTR 320        // padded K stride for h1 / emb table; h1 dir block at dir*160
#define GSTR 600        // gate row stride (u16), layout [jj][4 gates] interleaved
#define WK 160          // padded Whh K stride
#define L2E 1.442695041f
#define L2E2 2.885390082f

static __device__ __forceinline__ float bf2f(u16 u){
  unsigned v = ((unsigned)u) << 16;
  return __builtin_bit_cast(float, v);
}
static __device__ __forceinline__ u16 f2bf(float f){
  unsigned u = __builtin_bit_cast(unsigned, f);
  u = u + 0x7FFFu + ((u >> 16) & 1u);
  return (u16)(u >> 16);
}
// inputs PRE-SCALED by log2e (sig) / 2log2e (tanh)
static __device__ __forceinline__ float fsig2(float p){
  return __builtin_amdgcn_rcpf(1.0f + __builtin_amdgcn_exp2f(-p));
}
static __device__ __forceinline__ float ftanh2(float p){
  return 2.0f * __builtin_amdgcn_rcpf(1.0f + __builtin_amdgcn_exp2f(-p)) - 1.0f;
}

// ---------------- lengths from mask ----------------
__global__ void k_len(const int* __restrict__ mask, int* __restrict__ len){
  __shared__ int red[256];
  int b = blockIdx.x, t = threadIdx.x;
  red[t] = (mask[b*SS + t] != 0) ? 1 : 0;
  __syncthreads();
  for (int o = 128; o > 0; o >>= 1){
    if (t < o) red[t] += red[t+o];
    __syncthreads();
  }
  if (t == 0) len[b] = red[0];
}

// ---------------- deterministic rank sort by length (ascending) ----------------
__global__ void k_sort(const int* __restrict__ len, int* __restrict__ perm){
  __shared__ int L[1024];
  int b = threadIdx.x;
  int l = len[b];
  L[b] = l;
  __syncthreads();
  int r = 0;
  for (int j = 0; j < 1024; ++j){
    int lj = L[j];
    r += (lj < l) || (lj == l && j < b);
  }
  perm[r] = b;
}

// ---------------- weight pad/convert f32 -> bf16, gate-row pre-scale by log2e ----------------
// RM=1: remap input col c -> padded col (c<150 ? c : c+10)  (L1 Wih: dir blocks at 0,160)
struct PrepW {
  const float* src[8];
  u16* dst[8];
  int R[8], C[8], DR[8], DC[8], RM[8];
};
__global__ void k_prepw(PrepW p){
  int z = blockIdx.y;
  int n = p.DR[z]*p.DC[z];
  for (int i = blockIdx.x*256 + threadIdx.x; i < n; i += 800*256){
    int r = i / p.DC[z], c = i - r*p.DC[z];
    int cs = c; bool ok = true;
    if (p.RM[z]){
      if (c < 150)      cs = c;
      else if (c < 160) ok = false;     // pad between dir blocks
      else if (c < 310) cs = c - 10;
      else              ok = false;
    }
    float v = (ok && r < p.R[z] && cs < p.C[z]) ? p.src[z][r*p.C[z] + cs] : 0.f;
    float sc = (r >= 300 && r < 450) ? L2E2 : L2E;   // g-gate rows get 2*log2e
    p.dst[z][i] = f2bf(v * sc);
  }
}
struct PrepB { const float* src[4]; float* dst[4]; };
__global__ void k_prepb(PrepB p){
  int z = blockIdx.y;
  int i = blockIdx.x*256 + threadIdx.x;
  if (i < 640){
    float v = (i < GG) ? p.src[z][i] : 0.f;
    float sc = (i >= 300 && i < 450) ? L2E2 : L2E;
    p.dst[z][i] = v * sc;
  }
}

// ---------------- embedding table pad/convert: [VPAD][KSTR] bf16, row 0 zeroed ----------------
__global__ void k_prepemb(const float* __restrict__ emb, u16* __restrict__ dst){
  long i = (long)blockIdx.x*256 + threadIdx.x;
  if (i >= (long)VPAD*KSTR) return;
  int r = (int)(i / KSTR), c = (int)(i - (long)r*KSTR);
  float v = (r >= 1 && r < VV && c < DD) ? emb[(size_t)r*DD + c] : 0.f;
  dst[i] = f2bf(v);
}

// ---------------- register-fragment GEMM: no LDS, no barriers ----------------
__launch_bounds__(512, 2)
__global__ void k_gemm(const u16* __restrict__ A,
                       const u16* __restrict__ Wf, const u16* __restrict__ Wb,
                       const float* __restrict__ bsf, const float* __restrict__ bsb,
                       u16* __restrict__ of, u16* __restrict__ ob)
{
  const u16* W = blockIdx.z ? Wb : Wf;
  const float* bias = blockIdx.z ? bsb : bsf;
  u16* outp = blockIdx.z ? ob : of;

  int tid = threadIdx.x;
  int l = tid & 63, w = tid >> 6;
  int lo = l & 15, hi = l >> 4;
  int wm = w >> 2, wn = w & 3;
  int m0 = blockIdx.x * 128;
  int n0 = blockIdx.y * 320;

  const u16* Abase = A + (size_t)(m0 + wm*64 + lo)*KSTR + hi*8;
  const u16* Bbase = W + (size_t)(n0 + wn*80 + lo)*KSTR + hi*8;

  u16x8 avA[4], bvA[5], avB[4], bvB[5];
  #pragma unroll
  for (int mt = 0; mt < 4; ++mt) avA[mt] = *(const u16x8*)(Abase + (size_t)mt*16*KSTR);
  #pragma unroll
  for (int nt = 0; nt < 5; ++nt) bvA[nt] = *(const u16x8*)(Bbase + (size_t)nt*16*KSTR);

  f32x4 acc[4][5];
  #pragma unroll
  for (int a = 0; a < 4; ++a)
    #pragma unroll
    for (int b = 0; b < 5; ++b) acc[a][b] = (f32x4){0.f,0.f,0.f,0.f};

  for (int kk = 0; kk < 10; kk += 2){
    {
      int kc = (kk+1)*32;
      #pragma unroll
      for (int mt = 0; mt < 4; ++mt) avB[mt] = *(const u16x8*)(Abase + (size_t)mt*16*KSTR + kc);
      #pragma unroll
      for (int nt = 0; nt < 5; ++nt) bvB[nt] = *(const u16x8*)(Bbase + (size_t)nt*16*KSTR + kc);
    }
    #pragma unroll
    for (int mt = 0; mt < 4; ++mt)
      #pragma unroll
      for (int nt = 0; nt < 5; ++nt)
        acc[mt][nt] = __builtin_amdgcn_mfma_f32_16x16x32_bf16(
            __builtin_bit_cast(bf16x8, avA[mt]),
            __builtin_bit_cast(bf16x8, bvA[nt]),
            acc[mt][nt], 0, 0, 0);
    if (kk + 2 < 10){
      int kc = (kk+2)*32;
      #pragma unroll
      for (int mt = 0; mt < 4; ++mt) avA[mt] = *(const u16x8*)(Abase + (size_t)mt*16*KSTR + kc);
      #pragma unroll
      for (int nt = 0; nt < 5; ++nt) bvA[nt] = *(const u16x8*)(Bbase + (size_t)nt*16*KSTR + kc);
    }
    #pragma unroll
    for (int mt = 0; mt < 4; ++mt)
      #pragma unroll
      for (int nt = 0; nt < 5; ++nt)
        acc[mt][nt] = __builtin_amdgcn_mfma_f32_16x16x32_bf16(
            __builtin_bit_cast(bf16x8, avB[mt]),
            __builtin_bit_cast(bf16x8, bvB[nt]),
            acc[mt][nt], 0, 0, 0);
  }

  #pragma unroll
  for (int mt = 0; mt < 4; ++mt){
    #pragma unroll
    for (int nt = 0; nt < 5; ++nt){
      int col = n0 + wn*80 + nt*16 + lo;
      if (col < GG){
        float bsv = bias[col];
        int g = (col >= 450) ? 3 : (col >= 300) ? 2 : (col >= 150) ? 1 : 0;
        int cofs = (col - g*150)*4 + g;   // interleaved [jj][gate]
        #pragma unroll
        for (int r = 0; r < 4; ++r){
          int row = m0 + wm*64 + mt*16 + hi*4 + r;
          outp[(size_t)row*GSTR + cofs] = f2bf(acc[mt][nt][r] + bsv);
        }
      }
    }
  }
}

// ---------------- merged recurrence: LDS-staged h1 output, flush every 4 steps ----------------
#define PREF(GB, TT)                                                            \
  {                                                                             \
    _Pragma("unroll")                                                           \
    for (int r = 0; r < 4; ++r){                                                \
      int Li = Lr[r];                                                           \
      int tt = ((TT) < Li) ? (TT) : (Li-1);                                     \
      int s_ = dir ? (Li-1-tt) : tt;                                            \
      int rowi;                                                                 \
      if (isL1) rowi = rowb[r] + s_;                                            \
      else      rowi = (int)tks[(hi*4+r)*256 + s_];                             \
      GB[r] = *(const u16x4*)(xg + (size_t)rowi*GSTR + jjc*4);                  \
    }                                                                           \
  }

#define REC_STEP(T, PB, GB, Q, PG)                                              \
  {                                                                             \
    f32x4 acc0 = {0,0,0,0}, acc1 = {0,0,0,0}, acc2 = {0,0,0,0}, acc3 = {0,0,0,0}; \
    _Pragma("unroll")                                                           \
    for (int ks = 0; ks < 5; ++ks){                                             \
      u16x8 a_ = *(const u16x8*)&hsm[PB][lo*168 + ks*32 + hi*8];                \
      acc0 = __builtin_amdgcn_mfma_f32_16x16x32_bf16(                           \
          __builtin_bit_cast(bf16x8, a_), __builtin_bit_cast(bf16x8, bw[0][ks]), acc0, 0,0,0); \
      acc1 = __builtin_amdgcn_mfma_f32_16x16x32_bf16(                           \
          __builtin_bit_cast(bf16x8, a_), __builtin_bit_cast(bf16x8, bw[1][ks]), acc1, 0,0,0); \
      acc2 = __builtin_amdgcn_mfma_f32_16x16x32_bf16(                           \
          __builtin_bit_cast(bf16x8, a_), __builtin_bit_cast(bf16x8, bw[2][ks]), acc2, 0,0,0); \
      acc3 = __builtin_amdgcn_mfma_f32_16x16x32_bf16(                           \
          __builtin_bit_cast(bf16x8, a_), __builtin_bit_cast(bf16x8, bw[3][ks]), acc3, 0,0,0); \
    }                                                                           \
    _Pragma("unroll")                                                           \
    for (int r = 0; r < 4; ++r){                                                \
      if (jv && (T) < Lr[r]){                                                   \
        float pi  = acc0[r] + bf2f(GB[r][0]);                                   \
        float pf  = acc1[r] + bf2f(GB[r][1]);                                   \
        float pgv = acc2[r] + bf2f(GB[r][2]);                                   \
        float po  = acc3[r] + bf2f(GB[r][3]);                                   \
        float ig = fsig2(pi), fg = fsig2(pf), g2 = ftanh2(pgv), og = fsig2(po); \
        float cc = fg*cst[r] + ig*g2;  cst[r] = cc;                             \
        float hn = og * ftanh2(L2E2 * cc);                                      \
        u16 hb = f2bf(hn);                                                      \
        hsm[(PB)^1][(hi*4+r)*168 + jj] = hb;                                    \
        if (!isL1){                                                             \
          hout[PG][hi*4+r][Q][jj] = hb;                                         \
        } else {                                                                \
          bool isl = dir ? ((T)==0) : ((T)==Lr[r]-1);                           \
          if (isl) lastf[(size_t)bo2[r]*304 + dir*150 + jj] = hn;               \
        }                                                                       \
      }                                                                         \
    }                                                                           \
    if ((T)+4 < maxL){                                                          \
      PREF(GB, (T)+4)                                                           \
    }                                                                           \
    __builtin_amdgcn_sched_barrier(0);                                          \
    asm volatile("s_waitcnt lgkmcnt(0)" ::: "memory");                          \
    __builtin_amdgcn_s_barrier();                                               \
    __builtin_amdgcn_sched_barrier(0);                                          \
  }

// flush previous group's hout buffer: 64 rows (16 samples x 4 steps) x 19 u16x8 chunks
#define FLUSH(TB, PBF)                                                          \
  if (!isL1){                                                                   \
    _Pragma("unroll")                                                           \
    for (int pass = 0; pass < 2; ++pass){                                       \
      int task = tid + pass*640;                                                \
      if (task < 1216){                                                         \
        int i = task / 76; int rem = task - i*76;                               \
        int q = rem / 19;  int c8 = (rem - q*19)*8;                             \
        int Li = Ls[i]; int tt = (TB) + q;                                      \
        if (tt < Li && tt < maxL){                                              \
          int s_ = dir ? (Li-1-tt) : tt;                                        \
          *(u16x8*)(h1 + (size_t)(rbL[i]+s_)*KSTR + dir*160 + c8) =             \
              *(const u16x8*)&hout[PBF][i][q][c8];                              \
        }                                                                       \
      }                                                                         \
    }                                                                           \
  }

__launch_bounds__(640, 2)
__global__ void k_recM(const u16* __restrict__ gF, const u16* __restrict__ gBf,
                       const u16* __restrict__ tF, const u16* __restrict__ tB,
                       const u16* __restrict__ Wh0F, const u16* __restrict__ Wh0B,
                       const u16* __restrict__ Wh1F, const u16* __restrict__ Wh1B,
                       const int* __restrict__ len, const int* __restrict__ perm,
                       const int* __restrict__ x,
                       u16* __restrict__ h1, float* __restrict__ lastf,
                       int coA, int coB, int mode0)
{
  const int isL1 = (blockIdx.z == 0) ? mode0 : 0;
  const int dir  = blockIdx.y;
  const int tile = blockIdx.x;
  const int co   = isL1 ? coA : coB;
  const u16* xg  = isL1 ? (dir ? gBf : gF) : (dir ? tB : tF);
  const u16* Whh = isL1 ? (dir ? Wh1B : Wh1F) : (dir ? Wh0B : Wh0F);

  __shared__ u16 hsm[2][16*168];        // h dbuf for MFMA
  __shared__ u16 hout[2][16][4][152];   // staged h1 output, dbuf x 4 steps
  __shared__ u16 tks[16*256];
  __shared__ int Ls[16], rbL[16], boS[16];

  int tid = threadIdx.x;
  int l = tid & 63, w = tid >> 6;
  int lo = l & 15, hi = l >> 4;
  int jj = w*16 + lo;
  bool jv = (jj < HH);
  int jjc = jv ? jj : 0;

  u16x8 bw[4][5];
  #pragma unroll
  for (int g = 0; g < 4; ++g)
    #pragma unroll
    for (int ks = 0; ks < 5; ++ks)
      bw[g][ks] = *(const u16x8*)(Whh + (size_t)(g*150 + jj)*WK + ks*32 + hi*8);

  for (int i = tid; i < 2*16*168; i += 640) ((u16*)hsm)[i] = 0;
  for (int i = tid; i < 2*16*4*152; i += 640) ((u16*)hout)[i] = 0;  // pad cols stay finite
  if (tid < 16){
    int b = perm[co + tile*16 + tid];
    Ls[tid]  = len[b];
    rbL[tid] = (tile*16 + tid)*SS;
    boS[tid] = b;
  }
  __syncthreads();
  if (!isL1){
    for (int idx = tid; idx < 16*256; idx += 640){
      int i = idx >> 8, s = idx & 255;
      tks[idx] = (u16)x[boS[i]*SS + s];
    }
  }
  __syncthreads();

  int maxL = Ls[15];
  int Lr[4], rowb[4], bo2[4];
  #pragma unroll
  for (int r = 0; r < 4; ++r){
    int i = hi*4 + r;
    Lr[r] = Ls[i]; rowb[r] = rbL[i]; bo2[r] = boS[i];
  }

  float cst[4] = {0.f, 0.f, 0.f, 0.f};
  u16x4 g0[4], g1[4], g2b[4], g3[4];
  PREF(g0, 0)
  PREF(g1, 1)
  PREF(g2b, 2)
  PREF(g3, 3)

  for (int t = 0; t < maxL; t += 4){
    int page = (t >> 2) & 1;
    if (t >= 4){ FLUSH(t-4, page^1) }   // flush previous group (wide, coalesced)
    if (page == 0){
      REC_STEP(t, 0, g0, 0, 0)
      if (t + 1 < maxL) REC_STEP(t+1, 1, g1, 1, 0)
      if (t + 2 < maxL) REC_STEP(t+2, 0, g2b, 2, 0)
      if (t + 3 < maxL) REC_STEP(t+3, 1, g3, 3, 0)
    } else {
      REC_STEP(t, 0, g0, 0, 1)
      if (t + 1 < maxL) REC_STEP(t+1, 1, g1, 1, 1)
      if (t + 2 < maxL) REC_STEP(t+2, 0, g2b, 2, 1)
      if (t + 3 < maxL) REC_STEP(t+3, 1, g3, 3, 1)
    }
  }
  {
    int lastg = ((maxL-1) >> 2) << 2;
    int pbl   = ((maxL-1) >> 2) & 1;
    FLUSH(lastg, pbl)
  }
}

// ---------------- classifier head (fp32, float4) ----------------
__global__ void k_cls(const float* __restrict__ lastf,
                      const float* __restrict__ W1, const float* __restrict__ b1,
                      const float* __restrict__ W2, const float* __restrict__ b2,
                      float* __restrict__ out)
{
  __shared__ float inb[8][304];
  __shared__ float mid[8][304];
  int r0 = blockIdx.x * 8, tid = threadIdx.x;
  for (int i = tid; i < 8*76; i += 256){
    int r = i / 76, c4 = i - r*76;
    ((f4*)&inb[r][0])[c4] = ((const f4*)(lastf + (size_t)(r0+r)*304))[c4];
  }
  __syncthreads();
  for (int item = tid; item < 2400; item += 256){
    int r = item / 300, c = item - r*300;
    const f4* wr = (const f4*)(W1 + (size_t)c*300);
    const f4* xr = (const f4*)&inb[r][0];
    f4 a0 = {0,0,0,0}, a1 = {0,0,0,0}, a2 = {0,0,0,0};
    for (int k = 0; k < 75; k += 3){
      a0 += xr[k]   * wr[k];
      a1 += xr[k+1] * wr[k+1];
      a2 += xr[k+2] * wr[k+2];
    }
    f4 s4 = a0 + a1 + a2;
    float a = s4[0] + s4[1] + s4[2] + s4[3] + b1[c];
    mid[r][c] = 2.0f * __builtin_amdgcn_rcpf(1.0f + __builtin_amdgcn_exp2f(-L2E2*a)) - 1.0f;
  }
  __syncthreads();
  for (int item = tid; item < 2400; item += 256){
    int r = item / 300, c = item - r*300;
    const f4* wr = (const f4*)(W2 + (size_t)c*300);
    const f4* xr = (const f4*)&mid[r][0];
    f4 a0 = {0,0,0,0}, a1 = {0,0,0,0}, a2 = {0,0,0,0};
    for (int k = 0; k < 75; k += 3){
      a0 += xr[k]   * wr[k];
      a1 += xr[k+1] * wr[k+1];
      a2 += xr[k+2] * wr[k+2];
    }
    f4 s4 = a0 + a1 + a2;
    out[(size_t)(r0+r)*300 + c] = s4[0] + s4[1] + s4[2] + s4[3] + b2[c];
  }
}

extern "C" void kernel_launch(void* const* d_in, const int* in_sizes, int n_in,
                              void* d_out, int out_size, void* d_ws, size_t ws_size,
                              hipStream_t stream)
{
  const int*   x    = (const int*)d_in[0];
  const int*   mask = (const int*)d_in[1];
  const float* emb  = (const float*)d_in[2];
  const float* Wih[4] = {(const float*)d_in[3], (const float*)d_in[6],
                         (const float*)d_in[9], (const float*)d_in[12]};
  const float* Whh[4] = {(const float*)d_in[4], (const float*)d_in[7],
                         (const float*)d_in[10], (const float*)d_in[13]};
  const float* bs[4]  = {(const float*)d_in[5], (const float*)d_in[8],
                         (const float*)d_in[11], (const float*)d_in[14]};
  const float* W1 = (const float*)d_in[15];
  const float* b1 = (const float*)d_in[16];
  const float* W2 = (const float*)d_in[17];
  const float* b2 = (const float*)d_in[18];
  float* out = (float*)d_out;

  char* p = (char*)d_ws;
  auto alloc = [&](size_t bytes){ char* r = p; p += (bytes + 255) & ~(size_t)255; return r; };

  u16 *WihP[4], *WhhP[4];
  for (int i = 0; i < 4; ++i){
    WihP[i] = (u16*)alloc(640*320*2);
    WhhP[i] = (u16*)alloc(640*160*2);
  }
  float* biasP[4];
  for (int i = 0; i < 4; ++i) biasP[i] = (float*)alloc(640*4);
  int* len  = (int*)alloc(1024*4);
  int* perm = (int*)alloc(1024*4);
  float* lastf = (float*)alloc((size_t)1024*304*4);
  u16* embP = (u16*)alloc((size_t)VPAD*KSTR*2);
  u16* tabF = (u16*)alloc((size_t)VPAD*GSTR*2);
  u16* tabB = (u16*)alloc((size_t)VPAD*GSTR*2);
  size_t fixed_end = (size_t)(p - (char*)d_ws);

  const size_t per_sample = (size_t)SS*KSTR*2 + 2*(size_t)SS*GSTR*2;  // 778240 B
  int nc = 32;
  const int cands[6] = {1, 2, 4, 8, 16, 32};
  for (int ci = 0; ci < 6; ++ci){
    size_t need = fixed_end + (size_t)(BB / cands[ci]) * per_sample + (1u<<20);
    if (need <= ws_size){ nc = cands[ci]; break; }
  }
  const int Bc = BB / nc;
  const int Mc = Bc * SS;

  u16* h1    = (u16*)alloc((size_t)Mc*KSTR*2);
  u16* gateF = (u16*)alloc((size_t)Mc*GSTR*2);
  u16* gateB = (u16*)alloc((size_t)Mc*GSTR*2);

  (void)hipMemsetAsync(h1, 0, (size_t)Mc*KSTR*2, stream);   // pad cols must be zero/finite

  k_len <<<dim3(1024), dim3(256), 0, stream>>>(mask, len);
  k_sort<<<dim3(1),    dim3(1024),0, stream>>>(len, perm);

  PrepW pw;
  for (int i = 0; i < 4; ++i){
    pw.src[i] = Wih[i]; pw.dst[i] = WihP[i];
    pw.R[i] = GG; pw.C[i] = (i < 2) ? DD : 2*HH; pw.DR[i] = 640; pw.DC[i] = KSTR;
    pw.RM[i] = (i >= 2) ? 1 : 0;                      // L1 Wih: remap cols for dir*160 blocks
    pw.src[4+i] = Whh[i]; pw.dst[4+i] = WhhP[i];
    pw.R[4+i] = GG; pw.C[4+i] = HH; pw.DR[4+i] = 640; pw.DC[4+i] = WK;
    pw.RM[4+i] = 0;
  }
  k_prepw<<<dim3(800, 8), dim3(256), 0, stream>>>(pw);

  PrepB pb;
  for (int i = 0; i < 4; ++i){ pb.src[i] = bs[i]; pb.dst[i] = biasP[i]; }
  k_prepb<<<dim3(3, 4), dim3(256), 0, stream>>>(pb);

  k_prepemb<<<dim3((VPAD*KSTR + 255)/256), dim3(256), 0, stream>>>(emb, embP);

  k_gemm<<<dim3(VPAD/128, 2, 2), dim3(512), 0, stream>>>(embP, WihP[0], WihP[1],
                                                         biasP[0], biasP[1], tabF, tabB);

  k_recM<<<dim3(Bc/16, 2, 1), dim3(640), 0, stream>>>(gateF, gateB, tabF, tabB,
                                                      WhhP[0], WhhP[1], WhhP[2], WhhP[3],
                                                      len, perm, x, h1, lastf,
                                                      0, 0, /*mode0=*/0);
  k_gemm<<<dim3(Mc/128, 2, 2), dim3(512), 0, stream>>>(h1, WihP[2], WihP[3],
                                                       biasP[2], biasP[3], gateF, gateB);
  for (int c = 0; c < nc; ++c){
    if (c + 1 < nc){
      k_recM<<<dim3(Bc/16, 2, 2), dim3(640), 0, stream>>>(gateF, gateB, tabF, tabB,
                                                          WhhP[0], WhhP[1], WhhP[2], WhhP[3],
                                                          len, perm, x, h1, lastf,
                                                          c*Bc, (c+1)*Bc, /*mode0=*/1);
      k_gemm<<<dim3(Mc/128, 2, 2), dim3(512), 0, stream>>>(h1, WihP[2], WihP[3],
                                                           biasP[2], biasP[3], gateF, gateB);
    } else {
      k_recM<<<dim3(Bc/16, 2, 1), dim3(640), 0, stream>>>(gateF, gateB, tabF, tabB,
                                                          WhhP[0], WhhP[1], WhhP[2], WhhP[3],
                                                          len, perm, x, h1, lastf,
                                                          c*Bc, 0, /*mode0=*/1);
    }
  }

  k_cls<<<dim3(128), dim3(256), 0, stream>>>(lastf, W1, b1, W2, b2, out);
}

// Round 13
// 3864.868 us; speedup vs baseline: 2.5099x; 1.5383x over previous
//
#include <hip/hip_runtime.h>

typedef unsigned short u16;
typedef __bf16 bf16x8 __attribute__((ext_vector_type(8)));
typedef float f32x4 __attribute__((ext_vector_type(4)));
typedef float f4 __attribute__((ext_vector_type(4)));
typedef unsigned short u16x8 __attribute__((ext_vector_type(8)));
typedef unsigned short u16x4 __attribute__((ext_vector_type(4)));

#define BB 1024
#define SS 256
#define DD 300
#define HH 150
#define GG 600
#define VV 21257
#define VPAD 21376      // 167*128
#define KSTR 320        // padded K stride for h1 / emb table
#define GSTR 600        // gate row stride (u16), layout [jj][4 gates] interleaved
#define WK 160          // padded Whh K stride
#define L2E 1.442695041f
#define L2E2 2.885390082f

static __device__ __forceinline__ float bf2f(u16 u){
  unsigned v = ((unsigned)u) << 16;
  return __builtin_bit_cast(float, v);
}
static __device__ __forceinline__ u16 f2bf(float f){
  unsigned u = __builtin_bit_cast(unsigned, f);
  u = u + 0x7FFFu + ((u >> 16) & 1u);
  return (u16)(u >> 16);
}
// inputs PRE-SCALED by log2e (sig) / 2log2e (tanh)
static __device__ __forceinline__ float fsig2(float p){
  return __builtin_amdgcn_rcpf(1.0f + __builtin_amdgcn_exp2f(-p));
}
static __device__ __forceinline__ float ftanh2(float p){
  return 2.0f * __builtin_amdgcn_rcpf(1.0f + __builtin_amdgcn_exp2f(-p)) - 1.0f;
}

// ---------------- lengths from mask ----------------
__global__ void k_len(const int* __restrict__ mask, int* __restrict__ len){
  __shared__ int red[256];
  int b = blockIdx.x, t = threadIdx.x;
  red[t] = (mask[b*SS + t] != 0) ? 1 : 0;
  __syncthreads();
  for (int o = 128; o > 0; o >>= 1){
    if (t < o) red[t] += red[t+o];
    __syncthreads();
  }
  if (t == 0) len[b] = red[0];
}

// ---------------- deterministic rank sort by length (ascending) ----------------
__global__ void k_sort(const int* __restrict__ len, int* __restrict__ perm){
  __shared__ int L[1024];
  int b = threadIdx.x;
  int l = len[b];
  L[b] = l;
  __syncthreads();
  int r = 0;
  for (int j = 0; j < 1024; ++j){
    int lj = L[j];
    r += (lj < l) || (lj == l && j < b);
  }
  perm[r] = b;
}

// ---------------- weight pad/convert f32 -> bf16, gate-row pre-scale by log2e ----------------
struct PrepW {
  const float* src[8];
  u16* dst[8];
  int R[8], C[8], DR[8], DC[8];
};
__global__ void k_prepw(PrepW p){
  int z = blockIdx.y;
  int n = p.DR[z]*p.DC[z];
  for (int i = blockIdx.x*256 + threadIdx.x; i < n; i += 800*256){
    int r = i / p.DC[z], c = i - r*p.DC[z];
    float v = (r < p.R[z] && c < p.C[z]) ? p.src[z][r*p.C[z] + c] : 0.f;
    float sc = (r >= 300 && r < 450) ? L2E2 : L2E;   // g-gate rows get 2*log2e
    p.dst[z][i] = f2bf(v * sc);
  }
}
struct PrepB { const float* src[4]; float* dst[4]; };
__global__ void k_prepb(PrepB p){
  int z = blockIdx.y;
  int i = blockIdx.x*256 + threadIdx.x;
  if (i < 640){
    float v = (i < GG) ? p.src[z][i] : 0.f;
    float sc = (i >= 300 && i < 450) ? L2E2 : L2E;
    p.dst[z][i] = v * sc;
  }
}

// ---------------- embedding table pad/convert: [VPAD][KSTR] bf16, row 0 zeroed ----------------
__global__ void k_prepemb(const float* __restrict__ emb, u16* __restrict__ dst){
  long i = (long)blockIdx.x*256 + threadIdx.x;
  if (i >= (long)VPAD*KSTR) return;
  int r = (int)(i / KSTR), c = (int)(i - (long)r*KSTR);
  float v = (r >= 1 && r < VV && c < DD) ? emb[(size_t)r*DD + c] : 0.f;
  dst[i] = f2bf(v);
}

// ---------------- register-fragment GEMM: no LDS, no barriers ----------------
__launch_bounds__(512, 2)
__global__ void k_gemm(const u16* __restrict__ A,
                       const u16* __restrict__ Wf, const u16* __restrict__ Wb,
                       const float* __restrict__ bsf, const float* __restrict__ bsb,
                       u16* __restrict__ of, u16* __restrict__ ob)
{
  const u16* W = blockIdx.z ? Wb : Wf;
  const float* bias = blockIdx.z ? bsb : bsf;
  u16* outp = blockIdx.z ? ob : of;

  int tid = threadIdx.x;
  int l = tid & 63, w = tid >> 6;
  int lo = l & 15, hi = l >> 4;
  int wm = w >> 2, wn = w & 3;
  int m0 = blockIdx.x * 128;
  int n0 = blockIdx.y * 320;

  const u16* Abase = A + (size_t)(m0 + wm*64 + lo)*KSTR + hi*8;
  const u16* Bbase = W + (size_t)(n0 + wn*80 + lo)*KSTR + hi*8;

  u16x8 avA[4], bvA[5], avB[4], bvB[5];
  #pragma unroll
  for (int mt = 0; mt < 4; ++mt) avA[mt] = *(const u16x8*)(Abase + (size_t)mt*16*KSTR);
  #pragma unroll
  for (int nt = 0; nt < 5; ++nt) bvA[nt] = *(const u16x8*)(Bbase + (size_t)nt*16*KSTR);

  f32x4 acc[4][5];
  #pragma unroll
  for (int a = 0; a < 4; ++a)
    #pragma unroll
    for (int b = 0; b < 5; ++b) acc[a][b] = (f32x4){0.f,0.f,0.f,0.f};

  for (int kk = 0; kk < 10; kk += 2){
    {
      int kc = (kk+1)*32;
      #pragma unroll
      for (int mt = 0; mt < 4; ++mt) avB[mt] = *(const u16x8*)(Abase + (size_t)mt*16*KSTR + kc);
      #pragma unroll
      for (int nt = 0; nt < 5; ++nt) bvB[nt] = *(const u16x8*)(Bbase + (size_t)nt*16*KSTR + kc);
    }
    #pragma unroll
    for (int mt = 0; mt < 4; ++mt)
      #pragma unroll
      for (int nt = 0; nt < 5; ++nt)
        acc[mt][nt] = __builtin_amdgcn_mfma_f32_16x16x32_bf16(
            __builtin_bit_cast(bf16x8, avA[mt]),
            __builtin_bit_cast(bf16x8, bvA[nt]),
            acc[mt][nt], 0, 0, 0);
    if (kk + 2 < 10){
      int kc = (kk+2)*32;
      #pragma unroll
      for (int mt = 0; mt < 4; ++mt) avA[mt] = *(const u16x8*)(Abase + (size_t)mt*16*KSTR + kc);
      #pragma unroll
      for (int nt = 0; nt < 5; ++nt) bvA[nt] = *(const u16x8*)(Bbase + (size_t)nt*16*KSTR + kc);
    }
    #pragma unroll
    for (int mt = 0; mt < 4; ++mt)
      #pragma unroll
      for (int nt = 0; nt < 5; ++nt)
        acc[mt][nt] = __builtin_amdgcn_mfma_f32_16x16x32_bf16(
            __builtin_bit_cast(bf16x8, avB[mt]),
            __builtin_bit_cast(bf16x8, bvB[nt]),
            acc[mt][nt], 0, 0, 0);
  }

  #pragma unroll
  for (int mt = 0; mt < 4; ++mt){
    #pragma unroll
    for (int nt = 0; nt < 5; ++nt){
      int col = n0 + wn*80 + nt*16 + lo;
      if (col < GG){
        float bsv = bias[col];
        int g = (col >= 450) ? 3 : (col >= 300) ? 2 : (col >= 150) ? 1 : 0;
        int cofs = (col - g*150)*4 + g;   // interleaved [jj][gate]
        #pragma unroll
        for (int r = 0; r < 4; ++r){
          int row = m0 + wm*64 + mt*16 + hi*4 + r;
          outp[(size_t)row*GSTR + cofs] = f2bf(acc[mt][nt][r] + bsv);
        }
      }
    }
  }
}

// ---------------- merged recurrence (round-6 structure, NON-clobbering waits) ----------------
// KEY CHANGE vs round 6: asm waitcnt has NO "memory" clobber. The clobber forced the
// memory legalizer to drain vmcnt(0) every step (full HBM latency on the critical path,
// per round-10 ablation). Counted vmcnt waits now survive across barriers.
#define PREF(GB, TT)                                                            \
  {                                                                             \
    _Pragma("unroll")                                                           \
    for (int r = 0; r < 4; ++r){                                                \
      int Li = Lr[r];                                                           \
      int tt = ((TT) < Li) ? (TT) : (Li-1);                                     \
      int s_ = dir ? (Li-1-tt) : tt;                                            \
      int rowi;                                                                 \
      if (isL1) rowi = rowb[r] + s_;                                            \
      else      rowi = (int)tks[(hi*4+r)*256 + s_];                             \
      GB[r] = *(const u16x4*)(xg + (size_t)rowi*GSTR + jjc*4);                  \
    }                                                                           \
  }

#define REC_STEP(T, PB, GB)                                                     \
  {                                                                             \
    f32x4 acc0 = {0,0,0,0}, acc1 = {0,0,0,0}, acc2 = {0,0,0,0}, acc3 = {0,0,0,0}; \
    _Pragma("unroll")                                                           \
    for (int ks = 0; ks < 5; ++ks){                                             \
      u16x8 a_ = *(const u16x8*)&hsm[PB][lo*168 + ks*32 + hi*8];                \
      acc0 = __builtin_amdgcn_mfma_f32_16x16x32_bf16(                           \
          __builtin_bit_cast(bf16x8, a_), __builtin_bit_cast(bf16x8, bw[0][ks]), acc0, 0,0,0); \
      acc1 = __builtin_amdgcn_mfma_f32_16x16x32_bf16(                           \
          __builtin_bit_cast(bf16x8, a_), __builtin_bit_cast(bf16x8, bw[1][ks]), acc1, 0,0,0); \
      acc2 = __builtin_amdgcn_mfma_f32_16x16x32_bf16(                           \
          __builtin_bit_cast(bf16x8, a_), __builtin_bit_cast(bf16x8, bw[2][ks]), acc2, 0,0,0); \
      acc3 = __builtin_amdgcn_mfma_f32_16x16x32_bf16(                           \
          __builtin_bit_cast(bf16x8, a_), __builtin_bit_cast(bf16x8, bw[3][ks]), acc3, 0,0,0); \
    }                                                                           \
    _Pragma("unroll")                                                           \
    for (int r = 0; r < 4; ++r){                                                \
      if (jv && (T) < Lr[r]){                                                   \
        float pi  = acc0[r] + bf2f(GB[r][0]);                                   \
        float pf  = acc1[r] + bf2f(GB[r][1]);                                   \
        float pgv = acc2[r] + bf2f(GB[r][2]);                                   \
        float po  = acc3[r] + bf2f(GB[r][3]);                                   \
        float ig = fsig2(pi), fg = fsig2(pf), g2 = ftanh2(pgv), og = fsig2(po); \
        float cc = fg*cst[r] + ig*g2;  cst[r] = cc;                             \
        float hn = og * ftanh2(L2E2 * cc);                                      \
        u16 hb = f2bf(hn);                                                      \
        hsm[(PB)^1][(hi*4+r)*168 + jj] = hb;                                    \
        if (!isL1){                                                             \
          int s_ = dir ? (Lr[r]-1-(T)) : (T);                                   \
          h1[(size_t)(rowb[r]+s_)*KSTR + dir*150 + jj] = hb;                    \
        } else {                                                                \
          bool isl = dir ? ((T)==0) : ((T)==Lr[r]-1);                           \
          if (isl) lastf[(size_t)bo2[r]*304 + dir*150 + jj] = hn;               \
        }                                                                       \
      }                                                                         \
    }                                                                           \
    if ((T)+4 < maxL){                                                          \
      PREF(GB, (T)+4)                                                           \
    }                                                                           \
    __builtin_amdgcn_sched_barrier(0);                                          \
    asm volatile("s_waitcnt lgkmcnt(0)");                                       \
    __builtin_amdgcn_sched_barrier(0);                                          \
    __builtin_amdgcn_s_barrier();                                               \
    __builtin_amdgcn_sched_barrier(0);                                          \
  }

__launch_bounds__(640, 2)
__global__ void k_recM(const u16* __restrict__ gF, const u16* __restrict__ gBf,
                       const u16* __restrict__ tF, const u16* __restrict__ tB,
                       const u16* __restrict__ Wh0F, const u16* __restrict__ Wh0B,
                       const u16* __restrict__ Wh1F, const u16* __restrict__ Wh1B,
                       const int* __restrict__ len, const int* __restrict__ perm,
                       const int* __restrict__ x,
                       u16* __restrict__ h1, float* __restrict__ lastf,
                       int coA, int coB, int mode0)
{
  const int isL1 = (blockIdx.z == 0) ? mode0 : 0;
  const int dir  = blockIdx.y;
  const int tile = blockIdx.x;
  const int co   = isL1 ? coA : coB;
  const u16* xg  = isL1 ? (dir ? gBf : gF) : (dir ? tB : tF);
  const u16* Whh = isL1 ? (dir ? Wh1B : Wh1F) : (dir ? Wh0B : Wh0F);

  __shared__ u16 hsm[2][16*168];
  __shared__ u16 tks[16*256];
  __shared__ int Ls[16], rbL[16], boS[16];

  int tid = threadIdx.x;
  int l = tid & 63, w = tid >> 6;
  int lo = l & 15, hi = l >> 4;
  int jj = w*16 + lo;
  bool jv = (jj < HH);
  int jjc = jv ? jj : 0;

  u16x8 bw[4][5];
  #pragma unroll
  for (int g = 0; g < 4; ++g)
    #pragma unroll
    for (int ks = 0; ks < 5; ++ks)
      bw[g][ks] = *(const u16x8*)(Whh + (size_t)(g*150 + jj)*WK + ks*32 + hi*8);

  for (int i = tid; i < 2*16*168; i += 640) ((u16*)hsm)[i] = 0;
  if (tid < 16){
    int b = perm[co + tile*16 + tid];
    Ls[tid]  = len[b];
    rbL[tid] = (tile*16 + tid)*SS;
    boS[tid] = b;
  }
  __syncthreads();
  if (!isL1){
    for (int idx = tid; idx < 16*256; idx += 640){
      int i = idx >> 8, s = idx & 255;
      tks[idx] = (u16)x[boS[i]*SS + s];
    }
  }
  __syncthreads();

  int maxL = Ls[15];
  int Lr[4], rowb[4], bo2[4];
  #pragma unroll
  for (int r = 0; r < 4; ++r){
    int i = hi*4 + r;
    Lr[r] = Ls[i]; rowb[r] = rbL[i]; bo2[r] = boS[i];
  }

  float cst[4] = {0.f, 0.f, 0.f, 0.f};
  u16x4 g0[4], g1[4], g2b[4], g3[4];
  PREF(g0, 0)
  PREF(g1, 1)
  PREF(g2b, 2)
  PREF(g3, 3)

  for (int t = 0; t < maxL; t += 4){
    REC_STEP(t, 0, g0)
    if (t + 1 < maxL) REC_STEP(t+1, 1, g1)
    if (t + 2 < maxL) REC_STEP(t+2, 0, g2b)
    if (t + 3 < maxL) REC_STEP(t+3, 1, g3)
  }
}

// ---------------- classifier head (fp32, float4) ----------------
__global__ void k_cls(const float* __restrict__ lastf,
                      const float* __restrict__ W1, const float* __restrict__ b1,
                      const float* __restrict__ W2, const float* __restrict__ b2,
                      float* __restrict__ out)
{
  __shared__ float inb[8][304];
  __shared__ float mid[8][304];
  int r0 = blockIdx.x * 8, tid = threadIdx.x;
  for (int i = tid; i < 8*76; i += 256){
    int r = i / 76, c4 = i - r*76;
    ((f4*)&inb[r][0])[c4] = ((const f4*)(lastf + (size_t)(r0+r)*304))[c4];
  }
  __syncthreads();
  for (int item = tid; item < 2400; item += 256){
    int r = item / 300, c = item - r*300;
    const f4* wr = (const f4*)(W1 + (size_t)c*300);
    const f4* xr = (const f4*)&inb[r][0];
    f4 a0 = {0,0,0,0}, a1 = {0,0,0,0}, a2 = {0,0,0,0};
    for (int k = 0; k < 75; k += 3){
      a0 += xr[k]   * wr[k];
      a1 += xr[k+1] * wr[k+1];
      a2 += xr[k+2] * wr[k+2];
    }
    f4 s4 = a0 + a1 + a2;
    float a = s4[0] + s4[1] + s4[2] + s4[3] + b1[c];
    mid[r][c] = 2.0f * __builtin_amdgcn_rcpf(1.0f + __builtin_amdgcn_exp2f(-L2E2*a)) - 1.0f;
  }
  __syncthreads();
  for (int item = tid; item < 2400; item += 256){
    int r = item / 300, c = item - r*300;
    const f4* wr = (const f4*)(W2 + (size_t)c*300);
    const f4* xr = (const f4*)&mid[r][0];
    f4 a0 = {0,0,0,0}, a1 = {0,0,0,0}, a2 = {0,0,0,0};
    for (int k = 0; k < 75; k += 3){
      a0 += xr[k]   * wr[k];
      a1 += xr[k+1] * wr[k+1];
      a2 += xr[k+2] * wr[k+2];
    }
    f4 s4 = a0 + a1 + a2;
    out[(size_t)(r0+r)*300 + c] = s4[0] + s4[1] + s4[2] + s4[3] + b2[c];
  }
}

extern "C" void kernel_launch(void* const* d_in, const int* in_sizes, int n_in,
                              void* d_out, int out_size, void* d_ws, size_t ws_size,
                              hipStream_t stream)
{
  const int*   x    = (const int*)d_in[0];
  const int*   mask = (const int*)d_in[1];
  const float* emb  = (const float*)d_in[2];
  const float* Wih[4] = {(const float*)d_in[3], (const float*)d_in[6],
                         (const float*)d_in[9], (const float*)d_in[12]};
  const float* Whh[4] = {(const float*)d_in[4], (const float*)d_in[7],
                         (const float*)d_in[10], (const float*)d_in[13]};
  const float* bs[4]  = {(const float*)d_in[5], (const float*)d_in[8],
                         (const float*)d_in[11], (const float*)d_in[14]};
  const float* W1 = (const float*)d_in[15];
  const float* b1 = (const float*)d_in[16];
  const float* W2 = (const float*)d_in[17];
  const float* b2 = (const float*)d_in[18];
  float* out = (float*)d_out;

  char* p = (char*)d_ws;
  auto alloc = [&](size_t bytes){ char* r = p; p += (bytes + 255) & ~(size_t)255; return r; };

  u16 *WihP[4], *WhhP[4];
  for (int i = 0; i < 4; ++i){
    WihP[i] = (u16*)alloc(640*320*2);
    WhhP[i] = (u16*)alloc(640*160*2);
  }
  float* biasP[4];
  for (int i = 0; i < 4; ++i) biasP[i] = (float*)alloc(640*4);
  int* len  = (int*)alloc(1024*4);
  int* perm = (int*)alloc(1024*4);
  float* lastf = (float*)alloc((size_t)1024*304*4);
  u16* embP = (u16*)alloc((size_t)VPAD*KSTR*2);
  u16* tabF = (u16*)alloc((size_t)VPAD*GSTR*2);
  u16* tabB = (u16*)alloc((size_t)VPAD*GSTR*2);
  size_t fixed_end = (size_t)(p - (char*)d_ws);

  const size_t per_sample = (size_t)SS*KSTR*2 + 2*(size_t)SS*GSTR*2;  // 778240 B
  int nc = 32;
  const int cands[6] = {1, 2, 4, 8, 16, 32};
  for (int ci = 0; ci < 6; ++ci){
    size_t need = fixed_end + (size_t)(BB / cands[ci]) * per_sample + (1u<<20);
    if (need <= ws_size){ nc = cands[ci]; break; }
  }
  const int Bc = BB / nc;
  const int Mc = Bc * SS;

  u16* h1    = (u16*)alloc((size_t)Mc*KSTR*2);
  u16* gateF = (u16*)alloc((size_t)Mc*GSTR*2);
  u16* gateB = (u16*)alloc((size_t)Mc*GSTR*2);

  (void)hipMemsetAsync(h1, 0, (size_t)Mc*KSTR*2, stream);   // pad cols 300..319 must be 0

  k_len <<<dim3(1024), dim3(256), 0, stream>>>(mask, len);
  k_sort<<<dim3(1),    dim3(1024),0, stream>>>(len, perm);

  PrepW pw;
  for (int i = 0; i < 4; ++i){
    pw.src[i] = Wih[i]; pw.dst[i] = WihP[i];
    pw.R[i] = GG; pw.C[i] = DD; pw.DR[i] = 640; pw.DC[i] = KSTR;
    pw.src[4+i] = Whh[i]; pw.dst[4+i] = WhhP[i];
    pw.R[4+i] = GG; pw.C[4+i] = HH; pw.DR[4+i] = 640; pw.DC[4+i] = WK;
  }
  k_prepw<<<dim3(800, 8), dim3(256), 0, stream>>>(pw);

  PrepB pb;
  for (int i = 0; i < 4; ++i){ pb.src[i] = bs[i]; pb.dst[i] = biasP[i]; }
  k_prepb<<<dim3(3, 4), dim3(256), 0, stream>>>(pb);

  k_prepemb<<<dim3((VPAD*KSTR + 255)/256), dim3(256), 0, stream>>>(emb, embP);

  // token -> layer-0 x-gate tables (both dirs), bias folded, interleaved layout
  k_gemm<<<dim3(VPAD/128, 2, 2), dim3(512), 0, stream>>>(embP, WihP[0], WihP[1],
                                                         biasP[0], biasP[1], tabF, tabB);

  // chained pipeline: L0(c0) | G(c0) | [L1(c)+L0(c+1)] G(c+1) ... | L1(last)
  k_recM<<<dim3(Bc/16, 2, 1), dim3(640), 0, stream>>>(gateF, gateB, tabF, tabB,
                                                      WhhP[0], WhhP[1], WhhP[2], WhhP[3],
                                                      len, perm, x, h1, lastf,
                                                      0, 0, /*mode0=*/0);
  k_gemm<<<dim3(Mc/128, 2, 2), dim3(512), 0, stream>>>(h1, WihP[2], WihP[3],
                                                       biasP[2], biasP[3], gateF, gateB);
  for (int c = 0; c < nc; ++c){
    if (c + 1 < nc){
      k_recM<<<dim3(Bc/16, 2, 2), dim3(640), 0, stream>>>(gateF, gateB, tabF, tabB,
                                                          WhhP[0], WhhP[1], WhhP[2], WhhP[3],
                                                          len, perm, x, h1, lastf,
                                                          c*Bc, (c+1)*Bc, /*mode0=*/1);
      k_gemm<<<dim3(Mc/128, 2, 2), dim3(512), 0, stream>>>(h1, WihP[2], WihP[3],
                                                           biasP[2], biasP[3], gateF, gateB);
    } else {
      k_recM<<<dim3(Bc/16, 2, 1), dim3(640), 0, stream>>>(gateF, gateB, tabF, tabB,
                                                          WhhP[0], WhhP[1], WhhP[2], WhhP[3],
                                                          len, perm, x, h1, lastf,
                                                          c*Bc, 0, /*mode0=*/1);
    }
  }

  k_cls<<<dim3(128), dim3(256), 0, stream>>>(lastf, W1, b1, W2, b2, out);
}